// Round 3
// baseline (2155.795 us; speedup 1.0000x reference)
//
#include <hip/hip_runtime.h>
#include <hip/hip_bf16.h>

typedef unsigned short u16;
typedef unsigned int   u32;

#define NN 4096        // nodes
#define NE 262144      // edges
#define EMB 256
#define NH 4
#define HD 64

__device__ __forceinline__ float4 load4f(const float* p) { return *reinterpret_cast<const float4*>(p); }
__device__ __forceinline__ float sanitize_f(float v) {
  v = (v != v) ? 0.f : v;                 // nan -> 0
  return fminf(fmaxf(v, -1000.f), 1000.f); // +-inf and clip -> +-1000
}

// ---------------- GEMM: C[M,N] = act(A[M,K] @ W[N,K]^T + bias[N]) ----------------
// A/W/bias: f32, C: f32. M%64==0, N%64==0, K%16==0.
// ACT: 0 none, 1 sanitize, 2 leaky-relu(0.2)
template<int ACT>
__global__ __launch_bounds__(256) void gemm_bias(const float* __restrict__ A, const float* __restrict__ W,
                                                 const float* __restrict__ bias,
                                                 float* __restrict__ C, int M, int N, int K) {
  __shared__ float As[16][68];
  __shared__ float Bs[16][68];
  int tid = threadIdx.x;
  int bm = blockIdx.x * 64, bn = blockIdx.y * 64;
  int lr = tid >> 2;            // 0..63 load row
  int lk = (tid & 3) * 4;       // 0,4,8,12
  int ty = tid >> 4, tx = tid & 15;
  float acc[4][4] = {};
  for (int k0 = 0; k0 < K; k0 += 16) {
    float4 a4 = load4f(A + (size_t)(bm + lr) * K + k0 + lk);
    float4 b4 = load4f(W + (size_t)(bn + lr) * K + k0 + lk);
    As[lk+0][lr] = a4.x; As[lk+1][lr] = a4.y; As[lk+2][lr] = a4.z; As[lk+3][lr] = a4.w;
    Bs[lk+0][lr] = b4.x; Bs[lk+1][lr] = b4.y; Bs[lk+2][lr] = b4.z; Bs[lk+3][lr] = b4.w;
    __syncthreads();
#pragma unroll
    for (int kk = 0; kk < 16; kk++) {
      float4 av = *reinterpret_cast<const float4*>(&As[kk][ty*4]);
      float4 bv = *reinterpret_cast<const float4*>(&Bs[kk][tx*4]);
      float aa[4] = {av.x, av.y, av.z, av.w};
      float bb[4] = {bv.x, bv.y, bv.z, bv.w};
#pragma unroll
      for (int i = 0; i < 4; i++)
#pragma unroll
        for (int j = 0; j < 4; j++) acc[i][j] = fmaf(aa[i], bb[j], acc[i][j]);
    }
    __syncthreads();
  }
  float bj[4];
#pragma unroll
  for (int j = 0; j < 4; j++) bj[j] = bias[bn + tx*4 + j];
#pragma unroll
  for (int i = 0; i < 4; i++) {
    size_t ro = (size_t)(bm + ty*4 + i) * N + bn + tx*4;
#pragma unroll
    for (int j = 0; j < 4; j++) {
      float v = acc[i][j] + bj[j];
      if (ACT == 1) v = sanitize_f(v);
      if (ACT == 2) v = (v > 0.f) ? v : 0.2f * v;
      C[ro + j] = v;
    }
  }
}

// ---------------- causal MHA, flash style. qkv: (NN, 768) f32, out: (NN, 256) f32 ----------------
// block = 256 threads = 4 waves (one per head); blockIdx.x = query row.
__global__ __launch_bounds__(256) void mha_flash(const float* __restrict__ qkv, float* __restrict__ out) {
  __shared__ float q_s[NH][HD];
  int i = blockIdx.x;
  int tid = threadIdx.x;
  int h = tid >> 6, lane = tid & 63;
  q_s[h][lane] = qkv[(size_t)i * 768 + h * HD + lane];
  __syncthreads();
  float m = -INFINITY, s = 0.f, o = 0.f;
  for (int j0 = 0; j0 <= i; j0 += 64) {
    int nk = i - j0 + 1; if (nk > 64) nk = 64;
    float sc = -INFINITY;
    if (lane < nk) {
      const float* kr = qkv + (size_t)(j0 + lane) * 768 + 256 + h * HD;
      float acc = 0.f;
#pragma unroll
      for (int d = 0; d < HD; d += 4) {
        float4 k4 = load4f(kr + d);
        float4 q4 = *reinterpret_cast<const float4*>(&q_s[h][d]);
        acc = fmaf(k4.x, q4.x, acc); acc = fmaf(k4.y, q4.y, acc);
        acc = fmaf(k4.z, q4.z, acc); acc = fmaf(k4.w, q4.w, acc);
      }
      sc = acc * 0.125f;
    }
    float bm = sc;
#pragma unroll
    for (int off = 32; off; off >>= 1) bm = fmaxf(bm, __shfl_xor(bm, off));
    float mn = fmaxf(m, bm);
    float scale = __expf(m - mn);          // m=-inf first iter -> 0
    float p = (lane < nk) ? __expf(sc - mn) : 0.f;
    float ps = p;
#pragma unroll
    for (int off = 32; off; off >>= 1) ps += __shfl_xor(ps, off);
    s = s * scale + ps;
    o = o * scale;
    const float* vbp = qkv + (size_t)j0 * 768 + 512 + h * HD + lane;
    for (int jj = 0; jj < nk; jj++) {
      float pj = __shfl(p, jj);
      o = fmaf(pj, vbp[(size_t)jj * 768], o);
    }
    m = mn;
  }
  out[(size_t)i * EMB + h * HD + lane] = o / s;
}

// ---------------- CSR build ----------------
__global__ void zero_i32(int* p, int n) {
  int i = blockIdx.x * 256 + threadIdx.x;
  if (i < n) p[i] = 0;
}
__global__ void hist_dst(const int* __restrict__ adj, int* __restrict__ cnt) {
  int e = blockIdx.x * 256 + threadIdx.x;
  if (e < NE) atomicAdd(&cnt[adj[NE + e]], 1);
}
// 1 block, 1024 threads: exclusive scan of 4096 counts -> indptr[0..4096], cursor=indptr copy
__global__ __launch_bounds__(1024) void scan4096(const int* __restrict__ cnt, int* __restrict__ indptr,
                                                 int* __restrict__ cursor) {
  int t = threadIdx.x;
  int4 c = *reinterpret_cast<const int4*>(cnt + t * 4);
  int s0 = c.x, s1 = s0 + c.y, s2 = s1 + c.z, s3 = s2 + c.w;
  int lane = t & 63, w = t >> 6;
  int x = s3;
#pragma unroll
  for (int off = 1; off < 64; off <<= 1) {
    int y = __shfl_up(x, off);
    if (lane >= off) x += y;
  }
  __shared__ int wsum[16];
  if (lane == 63) wsum[w] = x;
  __syncthreads();
  if (t == 0) {
    int acc = 0;
    for (int i = 0; i < 16; i++) { int tv = wsum[i]; wsum[i] = acc; acc += tv; }
  }
  __syncthreads();
  int b = wsum[w] + x - s3;   // exclusive prefix for this thread's 4 bins
  indptr[t*4+0] = b;      indptr[t*4+1] = b + s0;
  indptr[t*4+2] = b + s1; indptr[t*4+3] = b + s2;
  cursor[t*4+0] = b;      cursor[t*4+1] = b + s0;
  cursor[t*4+2] = b + s1; cursor[t*4+3] = b + s2;
  if (t == 1023) indptr[4096] = b + s3;
}
__global__ void scatter_edges(const int* __restrict__ adj, int* __restrict__ cursor, int* __restrict__ esrc) {
  int e = blockIdx.x * 256 + threadIdx.x;
  if (e < NE) {
    int dst = adj[NE + e];
    int pos = atomicAdd(&cursor[dst], 1);
    esrc[pos] = adj[e];
  }
}

// ---------------- TransformerConv aggregation: y[n,:] += softmax-weighted sum over incoming edges -----
// block = 256 threads = 4 waves (head); blockIdx.x = dst node.
__global__ __launch_bounds__(256) void conv_agg(const float* __restrict__ qb, const float* __restrict__ kb,
                                                const float* __restrict__ vb, const int* __restrict__ indptr,
                                                const int* __restrict__ esrc, float* __restrict__ y) {
  __shared__ float q_s[EMB];
  int n = blockIdx.x;
  int tid = threadIdx.x;
  int h = tid >> 6, lane = tid & 63;
  q_s[tid] = qb[(size_t)n * EMB + tid];
  __syncthreads();
  int start = indptr[n], end = indptr[n + 1];
  float m = -INFINITY, s = 0.f, o = 0.f;
  for (int p0 = start; p0 < end; p0 += 64) {
    int nk = end - p0; if (nk > 64) nk = 64;
    int src = 0;
    float sc = -INFINITY;
    if (lane < nk) {
      src = esrc[p0 + lane];
      const float* kr = kb + (size_t)src * EMB + h * HD;
      const float* qh = &q_s[h * HD];
      float acc = 0.f;
#pragma unroll
      for (int d = 0; d < HD; d += 4) {
        float4 k4 = load4f(kr + d);
        float4 q4 = *reinterpret_cast<const float4*>(qh + d);
        acc = fmaf(k4.x, q4.x, acc); acc = fmaf(k4.y, q4.y, acc);
        acc = fmaf(k4.z, q4.z, acc); acc = fmaf(k4.w, q4.w, acc);
      }
      sc = acc * 0.125f;
    }
    float bm = sc;
#pragma unroll
    for (int off = 32; off; off >>= 1) bm = fmaxf(bm, __shfl_xor(bm, off));
    float mn = fmaxf(m, bm);
    float scale = __expf(m - mn);
    float p = (lane < nk) ? __expf(sc - mn) : 0.f;
    float ps = p;
#pragma unroll
    for (int off = 32; off; off >>= 1) ps += __shfl_xor(ps, off);
    s = s * scale + ps;
    o = o * scale;
    const float* vl = vb + h * HD + lane;
    for (int jj = 0; jj < nk; jj++) {
      int   sj = __shfl(src, jj);
      float pj = __shfl(p, jj);
      o = fmaf(pj, vl[(size_t)sj * EMB], o);
    }
    m = mn;
  }
  float agg = o / (s + 1e-16f);
  y[(size_t)n * EMB + h * HD + lane] += agg;   // skip connection already in y
}

// ---------------- instance norm (per-channel over nodes) + lrelu + sanitize -> f[:, colOff:colOff+256] ----
__global__ __launch_bounds__(256) void colstats_partial(const float* __restrict__ y, float* __restrict__ part) {
  int c = threadIdx.x;
  int r0 = blockIdx.x * 128;
  float s = 0.f, q = 0.f;
  for (int r = r0; r < r0 + 128; r++) {
    float v = y[(size_t)r * EMB + c];
    s += v; q = fmaf(v, v, q);
  }
  part[blockIdx.x * 512 + c] = s;
  part[blockIdx.x * 512 + 256 + c] = q;
}
__global__ __launch_bounds__(256) void colstats_final(const float* __restrict__ part, float* __restrict__ stats) {
  int c = threadIdx.x;
  float s = 0.f, q = 0.f;
  for (int b = 0; b < 32; b++) { s += part[b * 512 + c]; q += part[b * 512 + 256 + c]; }
  float mean = s * (1.f / 4096.f);
  float var  = q * (1.f / 4096.f) - mean * mean;
  stats[c] = mean;
  stats[256 + c] = rsqrtf(var + 1e-5f);
}
__global__ __launch_bounds__(256) void norm_apply(const float* __restrict__ y, const float* __restrict__ stats,
                                                  float* __restrict__ f, int colOff) {
  int c = threadIdx.x;
  float mean = stats[c], rstd = stats[256 + c];
  int r0 = blockIdx.x * 16;
  for (int r = r0; r < r0 + 16; r++) {
    float v = (y[(size_t)r * EMB + c] - mean) * rstd;
    v = (v > 0.f) ? v : 0.2f * v;
    v = sanitize_f(v);
    f[(size_t)r * 512 + colOff + c] = v;
  }
}

// ---------------- classifier tail: logits = f1 @ W2^T + b2 ; softmax ; write f32 ----------------
// block = 256 = 4 waves, each wave one row.
// out layout (f32): [0:8192] logits (4096x2), [8192:16384] probs (4096x2)
__global__ __launch_bounds__(256) void final_softmax(const float* __restrict__ f1, const float* __restrict__ W2,
                                                     const float* __restrict__ b2, float* __restrict__ out) {
  int w = threadIdx.x >> 6, lane = threadIdx.x & 63;
  int row = blockIdx.x * 4 + w;
  const float* fr = f1 + (size_t)row * 128;
  float x0 = fr[lane], x1 = fr[lane + 64];
  float p0 = x0 * W2[lane]       + x1 * W2[64 + lane];
  float p1 = x0 * W2[128 + lane] + x1 * W2[192 + lane];
#pragma unroll
  for (int off = 32; off; off >>= 1) { p0 += __shfl_xor(p0, off); p1 += __shfl_xor(p1, off); }
  if (lane == 0) {
    float l0 = p0 + b2[0], l1 = p1 + b2[1];
    float mx = fmaxf(l0, l1);
    float e0 = __expf(l0 - mx), e1 = __expf(l1 - mx);
    float inv = 1.f / (e0 + e1);
    out[(size_t)row * 2 + 0] = l0;
    out[(size_t)row * 2 + 1] = l1;
    out[8192 + (size_t)row * 2 + 0] = e0 * inv;
    out[8192 + (size_t)row * 2 + 1] = e1 * inv;
  }
}

extern "C" void kernel_launch(void* const* d_in, const int* in_sizes, int n_in,
                              void* d_out, int out_size, void* d_ws, size_t ws_size,
                              hipStream_t stream) {
  const float* img   = (const float*)d_in[2];
  const int*   adj   = (const int*)d_in[3];
  const float* W_img = (const float*)d_in[4];  const float* b_img = (const float*)d_in[5];
  const float* W_qkv = (const float*)d_in[6];  const float* b_qkv = (const float*)d_in[7];
  const float* W_o   = (const float*)d_in[8];  const float* b_o   = (const float*)d_in[9];
  const float* Wq_o  = (const float*)d_in[10]; const float* bq_o  = (const float*)d_in[11];
  const float* Wk_o  = (const float*)d_in[12]; const float* bk_o  = (const float*)d_in[13];
  const float* Wv_o  = (const float*)d_in[14]; const float* bv_o  = (const float*)d_in[15];
  const float* Ws_o  = (const float*)d_in[16]; const float* bs_o  = (const float*)d_in[17];
  const float* Wq_a  = (const float*)d_in[18]; const float* bq_a  = (const float*)d_in[19];
  const float* Wk_a  = (const float*)d_in[20]; const float* bk_a  = (const float*)d_in[21];
  const float* Wv_a  = (const float*)d_in[22]; const float* bv_a  = (const float*)d_in[23];
  const float* Ws_a  = (const float*)d_in[24]; const float* bs_a  = (const float*)d_in[25];
  const float* W_c1  = (const float*)d_in[26]; const float* b_c1  = (const float*)d_in[27];
  const float* W_c2  = (const float*)d_in[28]; const float* b_c2  = (const float*)d_in[29];

  char* ws = (char*)d_ws;
  float* h     = (float*)(ws + 0);                    // 4 MB   (4096x256)
  float* hattn = (float*)(ws + (4ull << 20));         // 4 MB
  float* qkv   = (float*)(ws + (8ull << 20));         // 12 MB  (4096x768; later conv q/k/v)
  float* y     = (float*)(ws + (20ull << 20));        // 4 MB   (mha out / conv y)
  float* f     = (float*)(ws + (24ull << 20));        // 8 MB   (4096x512 concat)
  float* f1    = (float*)(ws + (32ull << 20));        // 2 MB   (4096x128)
  int*   indptr= (int*)  (ws + (34ull << 20));        // 4097 ints
  int*   cursor= (int*)  (ws + (34ull << 20) + 20480);
  int*   esrc  = (int*)  (ws + (34ull << 20) + 40960);        // 1 MB
  float* part  = (float*)(ws + (34ull << 20) + 40960 + (1ull << 20)); // 64 KB
  float* stats = (float*)(ws + (34ull << 20) + 40960 + (1ull << 20) + 65536);

  float* qb = qkv;
  float* kb = qkv + (1u << 20);   // + 4096*256 floats
  float* vb = qkv + (2u << 20);

  dim3 b256(256);

  // 1. h = img_feat @ W_img^T + b_img
  gemm_bias<0><<<dim3(64, 4), b256, 0, stream>>>(img, W_img, b_img, h, NN, 256, 2048);
  // 2. qkv = h @ W_qkv^T + b_qkv
  gemm_bias<0><<<dim3(64, 12), b256, 0, stream>>>(h, W_qkv, b_qkv, qkv, NN, 768, 256);
  // 3. causal MHA -> y
  mha_flash<<<NN, b256, 0, stream>>>(qkv, y);
  // 4. h_attn = sanitize(y @ W_o^T + b_o)
  gemm_bias<1><<<dim3(64, 4), b256, 0, stream>>>(y, W_o, b_o, hattn, NN, 256, 256);
  // 5. CSR of video_adj_list grouped by dst
  zero_i32<<<16, b256, 0, stream>>>(cursor, NN);
  hist_dst<<<NE / 256, b256, 0, stream>>>(adj, cursor);
  scan4096<<<1, 1024, 0, stream>>>(cursor, indptr, cursor);
  scatter_edges<<<NE / 256, b256, 0, stream>>>(adj, cursor, esrc);

  // 6. conv path O (input h)
  gemm_bias<0><<<dim3(64, 4), b256, 0, stream>>>(h, Wq_o, bq_o, qb, NN, 256, 256);
  gemm_bias<0><<<dim3(64, 4), b256, 0, stream>>>(h, Wk_o, bk_o, kb, NN, 256, 256);
  gemm_bias<0><<<dim3(64, 4), b256, 0, stream>>>(h, Wv_o, bv_o, vb, NN, 256, 256);
  gemm_bias<0><<<dim3(64, 4), b256, 0, stream>>>(h, Ws_o, bs_o, y,  NN, 256, 256); // skip
  conv_agg<<<NN, b256, 0, stream>>>(qb, kb, vb, indptr, esrc, y);
  colstats_partial<<<32, b256, 0, stream>>>(y, part);
  colstats_final<<<1, b256, 0, stream>>>(part, stats);
  norm_apply<<<256, b256, 0, stream>>>(y, stats, f, 0);

  // 7. conv path A (input h_attn)
  gemm_bias<0><<<dim3(64, 4), b256, 0, stream>>>(hattn, Wq_a, bq_a, qb, NN, 256, 256);
  gemm_bias<0><<<dim3(64, 4), b256, 0, stream>>>(hattn, Wk_a, bk_a, kb, NN, 256, 256);
  gemm_bias<0><<<dim3(64, 4), b256, 0, stream>>>(hattn, Wv_a, bv_a, vb, NN, 256, 256);
  gemm_bias<0><<<dim3(64, 4), b256, 0, stream>>>(hattn, Ws_a, bs_a, y,  NN, 256, 256);
  conv_agg<<<NN, b256, 0, stream>>>(qb, kb, vb, indptr, esrc, y);
  colstats_partial<<<32, b256, 0, stream>>>(y, part);
  colstats_final<<<1, b256, 0, stream>>>(part, stats);
  norm_apply<<<256, b256, 0, stream>>>(y, stats, f, 256);

  // 8. f1 = lrelu(f @ W_c1^T + b_c1)
  gemm_bias<2><<<dim3(64, 2), b256, 0, stream>>>(f, W_c1, b_c1, f1, NN, 128, 512);
  // 9. logits + softmax -> out (f32): [0:8192] logits, [8192:16384] probs
  final_softmax<<<NN / 4, b256, 0, stream>>>(f1, W_c2, b_c2, (float*)d_out);
}

// Round 4
// 1109.362 us; speedup vs baseline: 1.9433x; 1.9433x over previous
//
#include <hip/hip_runtime.h>
#include <hip/hip_bf16.h>

typedef unsigned short u16;
typedef unsigned int   u32;
typedef __attribute__((ext_vector_type(8))) short short8;
typedef __attribute__((ext_vector_type(4))) float f32x4;

#define NN 4096        // nodes
#define NE 262144      // edges
#define EMB 256
#define NH 4
#define HD 64

__device__ __forceinline__ float4 load4f(const float* p) { return *reinterpret_cast<const float4*>(p); }
__device__ __forceinline__ float sanitize_f(float v) {
  v = (v != v) ? 0.f : v;                 // nan -> 0
  return fminf(fmaxf(v, -1000.f), 1000.f); // +-inf and clip -> +-1000
}
__device__ __forceinline__ u16 f2b_rne(float x) {          // f32 -> bf16 bits, round-nearest-even
  u32 b = __float_as_uint(x);
  b += 0x7fff + ((b >> 16) & 1);
  return (u16)(b >> 16);
}
__device__ __forceinline__ u32 pack2(float a, float b) {
  return (u32)f2b_rne(a) | ((u32)f2b_rne(b) << 16);
}

// ---------------- GEMM: C[M,N] = act(A[M,K] @ W[N,K]^T + bias[N]) ----------------
template<int ACT>
__global__ __launch_bounds__(256) void gemm_bias(const float* __restrict__ A, const float* __restrict__ W,
                                                 const float* __restrict__ bias,
                                                 float* __restrict__ C, int M, int N, int K) {
  __shared__ float As[16][68];
  __shared__ float Bs[16][68];
  int tid = threadIdx.x;
  int bm = blockIdx.x * 64, bn = blockIdx.y * 64;
  int lr = tid >> 2;            // 0..63 load row
  int lk = (tid & 3) * 4;       // 0,4,8,12
  int ty = tid >> 4, tx = tid & 15;
  float acc[4][4] = {};
  for (int k0 = 0; k0 < K; k0 += 16) {
    float4 a4 = load4f(A + (size_t)(bm + lr) * K + k0 + lk);
    float4 b4 = load4f(W + (size_t)(bn + lr) * K + k0 + lk);
    As[lk+0][lr] = a4.x; As[lk+1][lr] = a4.y; As[lk+2][lr] = a4.z; As[lk+3][lr] = a4.w;
    Bs[lk+0][lr] = b4.x; Bs[lk+1][lr] = b4.y; Bs[lk+2][lr] = b4.z; Bs[lk+3][lr] = b4.w;
    __syncthreads();
#pragma unroll
    for (int kk = 0; kk < 16; kk++) {
      float4 av = *reinterpret_cast<const float4*>(&As[kk][ty*4]);
      float4 bv = *reinterpret_cast<const float4*>(&Bs[kk][tx*4]);
      float aa[4] = {av.x, av.y, av.z, av.w};
      float bb[4] = {bv.x, bv.y, bv.z, bv.w};
#pragma unroll
      for (int i = 0; i < 4; i++)
#pragma unroll
        for (int j = 0; j < 4; j++) acc[i][j] = fmaf(aa[i], bb[j], acc[i][j]);
    }
    __syncthreads();
  }
  float bj[4];
#pragma unroll
  for (int j = 0; j < 4; j++) bj[j] = bias[bn + tx*4 + j];
#pragma unroll
  for (int i = 0; i < 4; i++) {
    size_t ro = (size_t)(bm + ty*4 + i) * N + bn + tx*4;
#pragma unroll
    for (int j = 0; j < 4; j++) {
      float v = acc[i][j] + bj[j];
      if (ACT == 1) v = sanitize_f(v);
      if (ACT == 2) v = (v > 0.f) ? v : 0.2f * v;
      C[ro + j] = v;
    }
  }
}

// ---------------- causal MHA via MFMA flash attention ----------------
// 1 wave per (16-row q-tile, head). blockIdx: head = bid&3, tile = 255-(bid>>2).
// qkv: (NN,768) f32 [Q|K|V]; out: (NN,256) f32.
// MFMA 16x16x32 bf16 layouts (gfx950, verified):
//   A: row=lane&15, k=(lane>>4)*8+j ; B: col=lane&15, k=(lane>>4)*8+j
//   C/D: col=lane&15, row=(lane>>4)*4+reg
#define KPAD 72   // 64 cols + 8 pad (shorts)
#define VPAD 40   // 32 cols + 8 pad (shorts)
__global__ __launch_bounds__(64) void mha_mfma(const float* __restrict__ qkv, float* __restrict__ out) {
  __shared__ short Ks[32 * KPAD];
  __shared__ short Qs[16 * KPAD];
  __shared__ short VTs[64 * VPAD];
  const int bid  = blockIdx.x;
  const int h    = bid & 3;
  const int tile = 255 - (bid >> 2);      // long tiles first
  const int q0   = tile * 16;
  const int l    = threadIdx.x;
  const int g    = l >> 4, r16 = l & 15;
  const int hofs = h * 64;

  // ---- stage Q tile (16 x 64) as bf16 ----
#pragma unroll
  for (int i = 0; i < 4; i++) {
    int idx = i * 64 + l;
    int row = idx >> 4, c4 = idx & 15;
    float4 v = load4f(qkv + (size_t)(q0 + row) * 768 + hofs + c4 * 4);
    *(uint2*)&Qs[row * KPAD + c4 * 4] = make_uint2(pack2(v.x, v.y), pack2(v.z, v.w));
  }
  __syncthreads();
  short8 Qf[2];
#pragma unroll
  for (int s = 0; s < 2; s++) Qf[s] = *(const short8*)&Qs[r16 * KPAD + 32 * s + 8 * g];

  f32x4 O0 = {0.f,0.f,0.f,0.f}, O1 = O0, O2 = O0, O3 = O0;   // O[16q][64d], nd blocks 0..3
  float m = -INFINITY, ssum = 0.f;                            // per q=r16, replicated over g

  const int kend = q0 + 15;
  for (int k0 = 0; k0 <= kend; k0 += 32) {
    // ---- stage K tile (32 x 64) ----
#pragma unroll
    for (int i = 0; i < 8; i++) {
      int idx = i * 64 + l;
      int row = idx >> 4, c4 = idx & 15;
      float4 v = load4f(qkv + (size_t)(k0 + row) * 768 + 256 + hofs + c4 * 4);
      *(uint2*)&Ks[row * KPAD + c4 * 4] = make_uint2(pack2(v.x, v.y), pack2(v.z, v.w));
    }
    // ---- stage V^T tile (64d x 32k) ----
#pragma unroll
    for (int it = 0; it < 2; it++) {
      int kb = it * 4 + g;                 // k-block 0..7 (4 k each)
      const float* vp = qkv + (size_t)(k0 + kb * 4) * 768 + 512 + hofs + r16 * 4;
      float4 a0 = load4f(vp);
      float4 a1 = load4f(vp + 768);
      float4 a2 = load4f(vp + 1536);
      float4 a3 = load4f(vp + 2304);
      int dbase = r16 * 4;
      *(uint2*)&VTs[(dbase + 0) * VPAD + kb * 4] = make_uint2(pack2(a0.x, a1.x), pack2(a2.x, a3.x));
      *(uint2*)&VTs[(dbase + 1) * VPAD + kb * 4] = make_uint2(pack2(a0.y, a1.y), pack2(a2.y, a3.y));
      *(uint2*)&VTs[(dbase + 2) * VPAD + kb * 4] = make_uint2(pack2(a0.z, a1.z), pack2(a2.z, a3.z));
      *(uint2*)&VTs[(dbase + 3) * VPAD + kb * 4] = make_uint2(pack2(a0.w, a1.w), pack2(a2.w, a3.w));
    }
    __syncthreads();

    // ---- QK^T: S^T[32k][16q], 2 m-blocks x 2 d-steps ----
    f32x4 S0 = {0.f,0.f,0.f,0.f}, S1 = {0.f,0.f,0.f,0.f};
#pragma unroll
    for (int s = 0; s < 2; s++) {
      short8 Kf0 = *(const short8*)&Ks[(r16)      * KPAD + 32 * s + 8 * g];
      short8 Kf1 = *(const short8*)&Ks[(16 + r16) * KPAD + 32 * s + 8 * g];
      S0 = __builtin_amdgcn_mfma_f32_16x16x32_bf16(Kf0, Qf[s], S0, 0, 0, 0);
      S1 = __builtin_amdgcn_mfma_f32_16x16x32_bf16(Kf1, Qf[s], S1, 0, 0, 0);
    }
    // lane holds S(q=r16, k_local = 16*mb + 4*g + r)
    float sc0[4], sc1[4];
#pragma unroll
    for (int r = 0; r < 4; r++) { sc0[r] = S0[r] * 0.125f; sc1[r] = S1[r] * 0.125f; }
    if (k0 + 31 > q0) {   // causal mask needed in this tile
#pragma unroll
      for (int r = 0; r < 4; r++) {
        if (k0 +      4 * g + r > q0 + r16) sc0[r] = -INFINITY;
        if (k0 + 16 + 4 * g + r > q0 + r16) sc1[r] = -INFINITY;
      }
    }
    // per-q tile max (reduce own 8, then across g-groups)
    float tm = sc0[0];
#pragma unroll
    for (int r = 1; r < 4; r++) tm = fmaxf(tm, sc0[r]);
#pragma unroll
    for (int r = 0; r < 4; r++) tm = fmaxf(tm, sc1[r]);
    tm = fmaxf(tm, __shfl_xor(tm, 16));
    tm = fmaxf(tm, __shfl_xor(tm, 32));
    float mn = fmaxf(m, tm);
    float ef = __expf(m - mn);            // 0 on first tile (m=-inf)
    float p0[4], p1[4];
#pragma unroll
    for (int r = 0; r < 4; r++) { p0[r] = __expf(sc0[r] - mn); p1[r] = __expf(sc1[r] - mn); }
    float ps = 0.f;
#pragma unroll
    for (int r = 0; r < 4; r++) ps += p0[r] + p1[r];
    ps += __shfl_xor(ps, 16);
    ps += __shfl_xor(ps, 32);
    ssum = ssum * ef + ps;
    m = mn;
    // rescale O accumulator: factor for q = 4*g + r, held by lane (4*g+r)
#pragma unroll
    for (int r = 0; r < 4; r++) {
      float efr = __shfl(ef, 4 * g + r);
      O0[r] *= efr; O1[r] *= efr; O2[r] *= efr; O3[r] *= efr;
    }
    // ---- build P A-fragment: a[j] = P(q=r16, k=8*g+j) ----
    short8 ap;
#pragma unroll
    for (int jb = 0; jb < 2; jb++) {
      int gs  = (2 * g + jb) & 3;
      int src = r16 + 16 * gs;
      int mbs = (2 * g + jb) >> 2;        // 0 or 1
#pragma unroll
      for (int rs = 0; rs < 4; rs++) {
        float t0 = __shfl(p0[rs], src);
        float t1 = __shfl(p1[rs], src);
        float tv = mbs ? t1 : t0;
        ap[jb * 4 + rs] = (short)f2b_rne(tv);
      }
    }
    // ---- PV: O[16q][64d] += P[16q][32k] @ V[32k][64d] ----
    {
      short8 Vf0 = *(const short8*)&VTs[(r16)      * VPAD + 8 * g];
      short8 Vf1 = *(const short8*)&VTs[(16 + r16) * VPAD + 8 * g];
      short8 Vf2 = *(const short8*)&VTs[(32 + r16) * VPAD + 8 * g];
      short8 Vf3 = *(const short8*)&VTs[(48 + r16) * VPAD + 8 * g];
      O0 = __builtin_amdgcn_mfma_f32_16x16x32_bf16(ap, Vf0, O0, 0, 0, 0);
      O1 = __builtin_amdgcn_mfma_f32_16x16x32_bf16(ap, Vf1, O1, 0, 0, 0);
      O2 = __builtin_amdgcn_mfma_f32_16x16x32_bf16(ap, Vf2, O2, 0, 0, 0);
      O3 = __builtin_amdgcn_mfma_f32_16x16x32_bf16(ap, Vf3, O3, 0, 0, 0);
    }
    __syncthreads();
  }
  // ---- finalize: divide by softmax sum and store ----
#pragma unroll
  for (int r = 0; r < 4; r++) {
    float invr = 1.0f / __shfl(ssum, 4 * g + r);
    size_t ro = (size_t)(q0 + 4 * g + r) * EMB + hofs + r16;
    out[ro +  0] = O0[r] * invr;
    out[ro + 16] = O1[r] * invr;
    out[ro + 32] = O2[r] * invr;
    out[ro + 48] = O3[r] * invr;
  }
}

// ---------------- CSR build ----------------
__global__ void zero_i32(int* p, int n) {
  int i = blockIdx.x * 256 + threadIdx.x;
  if (i < n) p[i] = 0;
}
__global__ void hist_dst(const int* __restrict__ adj, int* __restrict__ cnt) {
  int e = blockIdx.x * 256 + threadIdx.x;
  if (e < NE) atomicAdd(&cnt[adj[NE + e]], 1);
}
__global__ __launch_bounds__(1024) void scan4096(const int* __restrict__ cnt, int* __restrict__ indptr,
                                                 int* __restrict__ cursor) {
  int t = threadIdx.x;
  int4 c = *reinterpret_cast<const int4*>(cnt + t * 4);
  int s0 = c.x, s1 = s0 + c.y, s2 = s1 + c.z, s3 = s2 + c.w;
  int lane = t & 63, w = t >> 6;
  int x = s3;
#pragma unroll
  for (int off = 1; off < 64; off <<= 1) {
    int y = __shfl_up(x, off);
    if (lane >= off) x += y;
  }
  __shared__ int wsum[16];
  if (lane == 63) wsum[w] = x;
  __syncthreads();
  if (t == 0) {
    int acc = 0;
    for (int i = 0; i < 16; i++) { int tv = wsum[i]; wsum[i] = acc; acc += tv; }
  }
  __syncthreads();
  int b = wsum[w] + x - s3;
  indptr[t*4+0] = b;      indptr[t*4+1] = b + s0;
  indptr[t*4+2] = b + s1; indptr[t*4+3] = b + s2;
  cursor[t*4+0] = b;      cursor[t*4+1] = b + s0;
  cursor[t*4+2] = b + s1; cursor[t*4+3] = b + s2;
  if (t == 1023) indptr[4096] = b + s3;
}
__global__ void scatter_edges(const int* __restrict__ adj, int* __restrict__ cursor, int* __restrict__ esrc) {
  int e = blockIdx.x * 256 + threadIdx.x;
  if (e < NE) {
    int dst = adj[NE + e];
    int pos = atomicAdd(&cursor[dst], 1);
    esrc[pos] = adj[e];
  }
}

// ---------------- TransformerConv aggregation ----------------
__global__ __launch_bounds__(256) void conv_agg(const float* __restrict__ qb, const float* __restrict__ kb,
                                                const float* __restrict__ vb, const int* __restrict__ indptr,
                                                const int* __restrict__ esrc, float* __restrict__ y) {
  __shared__ float q_s[EMB];
  int n = blockIdx.x;
  int tid = threadIdx.x;
  int h = tid >> 6, lane = tid & 63;
  q_s[tid] = qb[(size_t)n * EMB + tid];
  __syncthreads();
  int start = indptr[n], end = indptr[n + 1];
  float m = -INFINITY, s = 0.f, o = 0.f;
  for (int p0 = start; p0 < end; p0 += 64) {
    int nk = end - p0; if (nk > 64) nk = 64;
    int src = 0;
    float sc = -INFINITY;
    if (lane < nk) {
      src = esrc[p0 + lane];
      const float* kr = kb + (size_t)src * EMB + h * HD;
      const float* qh = &q_s[h * HD];
      float acc = 0.f;
#pragma unroll
      for (int d = 0; d < HD; d += 4) {
        float4 k4 = load4f(kr + d);
        float4 q4 = *reinterpret_cast<const float4*>(qh + d);
        acc = fmaf(k4.x, q4.x, acc); acc = fmaf(k4.y, q4.y, acc);
        acc = fmaf(k4.z, q4.z, acc); acc = fmaf(k4.w, q4.w, acc);
      }
      sc = acc * 0.125f;
    }
    float bm = sc;
#pragma unroll
    for (int off = 32; off; off >>= 1) bm = fmaxf(bm, __shfl_xor(bm, off));
    float mn = fmaxf(m, bm);
    float scale = __expf(m - mn);
    float p = (lane < nk) ? __expf(sc - mn) : 0.f;
    float ps = p;
#pragma unroll
    for (int off = 32; off; off >>= 1) ps += __shfl_xor(ps, off);
    s = s * scale + ps;
    o = o * scale;
    const float* vl = vb + h * HD + lane;
    for (int jj = 0; jj < nk; jj++) {
      int   sj = __shfl(src, jj);
      float pj = __shfl(p, jj);
      o = fmaf(pj, vl[(size_t)sj * EMB], o);
    }
    m = mn;
  }
  float agg = o / (s + 1e-16f);
  y[(size_t)n * EMB + h * HD + lane] += agg;
}

// ---------------- instance norm + lrelu + sanitize ----------------
__global__ __launch_bounds__(256) void colstats_partial(const float* __restrict__ y, float* __restrict__ part) {
  int c = threadIdx.x;
  int r0 = blockIdx.x * 128;
  float s = 0.f, q = 0.f;
  for (int r = r0; r < r0 + 128; r++) {
    float v = y[(size_t)r * EMB + c];
    s += v; q = fmaf(v, v, q);
  }
  part[blockIdx.x * 512 + c] = s;
  part[blockIdx.x * 512 + 256 + c] = q;
}
__global__ __launch_bounds__(256) void colstats_final(const float* __restrict__ part, float* __restrict__ stats) {
  int c = threadIdx.x;
  float s = 0.f, q = 0.f;
  for (int b = 0; b < 32; b++) { s += part[b * 512 + c]; q += part[b * 512 + 256 + c]; }
  float mean = s * (1.f / 4096.f);
  float var  = q * (1.f / 4096.f) - mean * mean;
  stats[c] = mean;
  stats[256 + c] = rsqrtf(var + 1e-5f);
}
__global__ __launch_bounds__(256) void norm_apply(const float* __restrict__ y, const float* __restrict__ stats,
                                                  float* __restrict__ f, int colOff) {
  int c = threadIdx.x;
  float mean = stats[c], rstd = stats[256 + c];
  int r0 = blockIdx.x * 16;
  for (int r = r0; r < r0 + 16; r++) {
    float v = (y[(size_t)r * EMB + c] - mean) * rstd;
    v = (v > 0.f) ? v : 0.2f * v;
    v = sanitize_f(v);
    f[(size_t)r * 512 + colOff + c] = v;
  }
}

// ---------------- classifier tail ----------------
__global__ __launch_bounds__(256) void final_softmax(const float* __restrict__ f1, const float* __restrict__ W2,
                                                     const float* __restrict__ b2, float* __restrict__ out) {
  int w = threadIdx.x >> 6, lane = threadIdx.x & 63;
  int row = blockIdx.x * 4 + w;
  const float* fr = f1 + (size_t)row * 128;
  float x0 = fr[lane], x1 = fr[lane + 64];
  float p0 = x0 * W2[lane]       + x1 * W2[64 + lane];
  float p1 = x0 * W2[128 + lane] + x1 * W2[192 + lane];
#pragma unroll
  for (int off = 32; off; off >>= 1) { p0 += __shfl_xor(p0, off); p1 += __shfl_xor(p1, off); }
  if (lane == 0) {
    float l0 = p0 + b2[0], l1 = p1 + b2[1];
    float mx = fmaxf(l0, l1);
    float e0 = __expf(l0 - mx), e1 = __expf(l1 - mx);
    float inv = 1.f / (e0 + e1);
    out[(size_t)row * 2 + 0] = l0;
    out[(size_t)row * 2 + 1] = l1;
    out[8192 + (size_t)row * 2 + 0] = e0 * inv;
    out[8192 + (size_t)row * 2 + 1] = e1 * inv;
  }
}

extern "C" void kernel_launch(void* const* d_in, const int* in_sizes, int n_in,
                              void* d_out, int out_size, void* d_ws, size_t ws_size,
                              hipStream_t stream) {
  const float* img   = (const float*)d_in[2];
  const int*   adj   = (const int*)d_in[3];
  const float* W_img = (const float*)d_in[4];  const float* b_img = (const float*)d_in[5];
  const float* W_qkv = (const float*)d_in[6];  const float* b_qkv = (const float*)d_in[7];
  const float* W_o   = (const float*)d_in[8];  const float* b_o   = (const float*)d_in[9];
  const float* Wq_o  = (const float*)d_in[10]; const float* bq_o  = (const float*)d_in[11];
  const float* Wk_o  = (const float*)d_in[12]; const float* bk_o  = (const float*)d_in[13];
  const float* Wv_o  = (const float*)d_in[14]; const float* bv_o  = (const float*)d_in[15];
  const float* Ws_o  = (const float*)d_in[16]; const float* bs_o  = (const float*)d_in[17];
  const float* Wq_a  = (const float*)d_in[18]; const float* bq_a  = (const float*)d_in[19];
  const float* Wk_a  = (const float*)d_in[20]; const float* bk_a  = (const float*)d_in[21];
  const float* Wv_a  = (const float*)d_in[22]; const float* bv_a  = (const float*)d_in[23];
  const float* Ws_a  = (const float*)d_in[24]; const float* bs_a  = (const float*)d_in[25];
  const float* W_c1  = (const float*)d_in[26]; const float* b_c1  = (const float*)d_in[27];
  const float* W_c2  = (const float*)d_in[28]; const float* b_c2  = (const float*)d_in[29];

  char* ws = (char*)d_ws;
  float* h     = (float*)(ws + 0);
  float* hattn = (float*)(ws + (4ull << 20));
  float* qkv   = (float*)(ws + (8ull << 20));
  float* y     = (float*)(ws + (20ull << 20));
  float* f     = (float*)(ws + (24ull << 20));
  float* f1    = (float*)(ws + (32ull << 20));
  int*   indptr= (int*)  (ws + (34ull << 20));
  int*   cursor= (int*)  (ws + (34ull << 20) + 20480);
  int*   esrc  = (int*)  (ws + (34ull << 20) + 40960);
  float* part  = (float*)(ws + (34ull << 20) + 40960 + (1ull << 20));
  float* stats = (float*)(ws + (34ull << 20) + 40960 + (1ull << 20) + 65536);

  float* qb = qkv;
  float* kb = qkv + (1u << 20);
  float* vb = qkv + (2u << 20);

  dim3 b256(256);

  // 1. h = img_feat @ W_img^T + b_img
  gemm_bias<0><<<dim3(64, 4), b256, 0, stream>>>(img, W_img, b_img, h, NN, 256, 2048);
  // 2. qkv = h @ W_qkv^T + b_qkv
  gemm_bias<0><<<dim3(64, 12), b256, 0, stream>>>(h, W_qkv, b_qkv, qkv, NN, 768, 256);
  // 3. causal MHA (MFMA flash) -> y
  mha_mfma<<<1024, 64, 0, stream>>>(qkv, y);
  // 4. h_attn = sanitize(y @ W_o^T + b_o)
  gemm_bias<1><<<dim3(64, 4), b256, 0, stream>>>(y, W_o, b_o, hattn, NN, 256, 256);
  // 5. CSR of video_adj_list grouped by dst
  zero_i32<<<16, b256, 0, stream>>>(cursor, NN);
  hist_dst<<<NE / 256, b256, 0, stream>>>(adj, cursor);
  scan4096<<<1, 1024, 0, stream>>>(cursor, indptr, cursor);
  scatter_edges<<<NE / 256, b256, 0, stream>>>(adj, cursor, esrc);

  // 6. conv path O (input h)
  gemm_bias<0><<<dim3(64, 4), b256, 0, stream>>>(h, Wq_o, bq_o, qb, NN, 256, 256);
  gemm_bias<0><<<dim3(64, 4), b256, 0, stream>>>(h, Wk_o, bk_o, kb, NN, 256, 256);
  gemm_bias<0><<<dim3(64, 4), b256, 0, stream>>>(h, Wv_o, bv_o, vb, NN, 256, 256);
  gemm_bias<0><<<dim3(64, 4), b256, 0, stream>>>(h, Ws_o, bs_o, y,  NN, 256, 256);
  conv_agg<<<NN, b256, 0, stream>>>(qb, kb, vb, indptr, esrc, y);
  colstats_partial<<<32, b256, 0, stream>>>(y, part);
  colstats_final<<<1, b256, 0, stream>>>(part, stats);
  norm_apply<<<256, b256, 0, stream>>>(y, stats, f, 0);

  // 7. conv path A (input h_attn)
  gemm_bias<0><<<dim3(64, 4), b256, 0, stream>>>(hattn, Wq_a, bq_a, qb, NN, 256, 256);
  gemm_bias<0><<<dim3(64, 4), b256, 0, stream>>>(hattn, Wk_a, bk_a, kb, NN, 256, 256);
  gemm_bias<0><<<dim3(64, 4), b256, 0, stream>>>(hattn, Wv_a, bv_a, vb, NN, 256, 256);
  gemm_bias<0><<<dim3(64, 4), b256, 0, stream>>>(hattn, Ws_a, bs_a, y,  NN, 256, 256);
  conv_agg<<<NN, b256, 0, stream>>>(qb, kb, vb, indptr, esrc, y);
  colstats_partial<<<32, b256, 0, stream>>>(y, part);
  colstats_final<<<1, b256, 0, stream>>>(part, stats);
  norm_apply<<<256, b256, 0, stream>>>(y, stats, f, 256);

  // 8. f1 = lrelu(f @ W_c1^T + b_c1)
  gemm_bias<2><<<dim3(64, 2), b256, 0, stream>>>(f, W_c1, b_c1, f1, NN, 128, 512);
  // 9. logits + softmax -> out (f32): [0:8192] logits, [8192:16384] probs
  final_softmax<<<NN / 4, b256, 0, stream>>>(f1, W_c2, b_c2, (float*)d_out);
}

// Round 5
// 619.168 us; speedup vs baseline: 3.4818x; 1.7917x over previous
//
#include <hip/hip_runtime.h>
#include <hip/hip_bf16.h>

typedef unsigned short u16;
typedef unsigned int   u32;
typedef __attribute__((ext_vector_type(8))) short short8;
typedef __attribute__((ext_vector_type(4))) float f32x4;

#define NN 4096        // nodes
#define NE 262144      // edges
#define EMB 256
#define NH 4
#define HD 64

__device__ __forceinline__ float4 load4f(const float* p) { return *reinterpret_cast<const float4*>(p); }
__device__ __forceinline__ float sanitize_f(float v) {
  v = (v != v) ? 0.f : v;                 // nan -> 0
  return fminf(fmaxf(v, -1000.f), 1000.f); // +-inf and clip -> +-1000
}
__device__ __forceinline__ u16 f2b_rne(float x) {          // f32 -> bf16 bits, round-nearest-even
  u32 b = __float_as_uint(x);
  b += 0x7fff + ((b >> 16) & 1);
  return (u16)(b >> 16);
}
__device__ __forceinline__ u32 pack2(float a, float b) {
  return (u32)f2b_rne(a) | ((u32)f2b_rne(b) << 16);
}

// ---------------- GEMM: C[M,N] = act(A[M,K] @ W[N,K]^T + bias[N]) ----------------
template<int ACT>
__global__ __launch_bounds__(256) void gemm_bias(const float* __restrict__ A, const float* __restrict__ W,
                                                 const float* __restrict__ bias,
                                                 float* __restrict__ C, int M, int N, int K) {
  __shared__ float As[16][68];
  __shared__ float Bs[16][68];
  int tid = threadIdx.x;
  int bm = blockIdx.x * 64, bn = blockIdx.y * 64;
  int lr = tid >> 2;            // 0..63 load row
  int lk = (tid & 3) * 4;       // 0,4,8,12
  int ty = tid >> 4, tx = tid & 15;
  float acc[4][4] = {};
  for (int k0 = 0; k0 < K; k0 += 16) {
    float4 a4 = load4f(A + (size_t)(bm + lr) * K + k0 + lk);
    float4 b4 = load4f(W + (size_t)(bn + lr) * K + k0 + lk);
    As[lk+0][lr] = a4.x; As[lk+1][lr] = a4.y; As[lk+2][lr] = a4.z; As[lk+3][lr] = a4.w;
    Bs[lk+0][lr] = b4.x; Bs[lk+1][lr] = b4.y; Bs[lk+2][lr] = b4.z; Bs[lk+3][lr] = b4.w;
    __syncthreads();
#pragma unroll
    for (int kk = 0; kk < 16; kk++) {
      float4 av = *reinterpret_cast<const float4*>(&As[kk][ty*4]);
      float4 bv = *reinterpret_cast<const float4*>(&Bs[kk][tx*4]);
      float aa[4] = {av.x, av.y, av.z, av.w};
      float bb[4] = {bv.x, bv.y, bv.z, bv.w};
#pragma unroll
      for (int i = 0; i < 4; i++)
#pragma unroll
        for (int j = 0; j < 4; j++) acc[i][j] = fmaf(aa[i], bb[j], acc[i][j]);
    }
    __syncthreads();
  }
  float bj[4];
#pragma unroll
  for (int j = 0; j < 4; j++) bj[j] = bias[bn + tx*4 + j];
#pragma unroll
  for (int i = 0; i < 4; i++) {
    size_t ro = (size_t)(bm + ty*4 + i) * N + bn + tx*4;
#pragma unroll
    for (int j = 0; j < 4; j++) {
      float v = acc[i][j] + bj[j];
      if (ACT == 1) v = sanitize_f(v);
      if (ACT == 2) v = (v > 0.f) ? v : 0.2f * v;
      C[ro + j] = v;
    }
  }
}

// ---------------- qkv f32 -> bf16 converts ----------------
// qkb[n][512] = bf16(qkv[n][0:512])  (Q|K)
__global__ __launch_bounds__(256) void conv_qk(const float* __restrict__ qkv, u16* __restrict__ qkb) {
  int i = (blockIdx.x * 256 + threadIdx.x) * 8;
  int n = i >> 9, c = i & 511;
  const float* p = qkv + (size_t)n * 768 + c;
  float4 a = load4f(p), b = load4f(p + 4);
  uint4 r = make_uint4(pack2(a.x, a.y), pack2(a.z, a.w), pack2(b.x, b.y), pack2(b.z, b.w));
  *(uint4*)&qkb[(size_t)n * 512 + c] = r;
}
// vtb[c][n] = bf16(qkv[n][512+c]), c in [0,256): V transposed, row = h*64+d
__global__ __launch_bounds__(256) void conv_vt(const float* __restrict__ qkv, u16* __restrict__ vtb) {
  __shared__ u16 T[64][72];
  int t = threadIdx.x;
  int n0 = (blockIdx.x >> 2) * 64, c0 = (blockIdx.x & 3) * 64;
#pragma unroll
  for (int it = 0; it < 4; it++) {
    int nl = it * 16 + (t >> 4), c4 = (t & 15) * 4;
    float4 v = load4f(qkv + (size_t)(n0 + nl) * 768 + 512 + c0 + c4);
    T[nl][c4] = f2b_rne(v.x); T[nl][c4+1] = f2b_rne(v.y);
    T[nl][c4+2] = f2b_rne(v.z); T[nl][c4+3] = f2b_rne(v.w);
  }
  __syncthreads();
  int cl = t >> 2, chunk = t & 3;
  u16 buf[16];
#pragma unroll
  for (int j = 0; j < 16; j++) buf[j] = T[chunk * 16 + j][cl];
  *(uint4*)&vtb[(size_t)(c0 + cl) * 4096 + n0 + chunk * 16]     = *(uint4*)&buf[0];
  *(uint4*)&vtb[(size_t)(c0 + cl) * 4096 + n0 + chunk * 16 + 8] = *(uint4*)&buf[8];
}

// ---------------- causal MHA: MFMA flash, split-K over 4 waves ----------------
// grid 1024: head = bid&3, qtile = 255-(bid>>2) (16 rows). 4 waves stripe 64-key ktiles.
// Fragment maps (verified on-device in round 4):
//   A: row=lane&15, k=8*(lane>>4)+j ; B: col=lane&15, same k ; C/D: col=lane&15, row=4*(lane>>4)+reg
__global__ __launch_bounds__(256, 4) void mha_mfma2(const u16* __restrict__ qkb, const u16* __restrict__ vtb,
                                                    float* __restrict__ out) {
  __shared__ float Obuf[4][16][68];
  __shared__ float msh[4][16];
  __shared__ float ssh[4][16];
  const int bid  = blockIdx.x;
  const int h    = bid & 3;
  const int tile = 255 - (bid >> 2);
  const int q0   = tile * 16;
  const int w    = threadIdx.x >> 6;
  const int l    = threadIdx.x & 63;
  const int g    = l >> 4, r16 = l & 15;
  const int hofs = h * 64;

  // Q B-fragments: col=q=r16, dims 32s+8g+j
  const u16* qrow = qkb + (size_t)(q0 + r16) * 512 + hofs;
  short8 Qf0 = *(const short8*)&qrow[8 * g];
  short8 Qf1 = *(const short8*)&qrow[32 + 8 * g];

  f32x4 O0 = {0.f,0.f,0.f,0.f}, O1 = O0, O2 = O0, O3 = O0;  // O[16q][64d] 4 d-blocks
  float m = -INFINITY, ssum = 0.f;
  const int nkt = (q0 + 16 + 63) >> 6;

  for (int kt = w; kt < nkt; kt += 4) {
    const int k0 = kt * 64;
    // ---- S^T[64k][16q]: 4 m-blocks, K rows direct from global ----
    f32x4 S0 = {0.f,0.f,0.f,0.f}, S1 = S0, S2 = S0, S3 = S0;
    {
      const u16* kb0 = qkb + (size_t)(k0 + r16) * 512 + 256 + hofs + 8 * g;
      short8 a0 = *(const short8*)&kb0[0];
      short8 b0 = *(const short8*)&kb0[32];
      const u16* kb1 = kb0 + (size_t)16 * 512;
      short8 a1 = *(const short8*)&kb1[0];
      short8 b1 = *(const short8*)&kb1[32];
      const u16* kb2 = kb1 + (size_t)16 * 512;
      short8 a2 = *(const short8*)&kb2[0];
      short8 b2 = *(const short8*)&kb2[32];
      const u16* kb3 = kb2 + (size_t)16 * 512;
      short8 a3 = *(const short8*)&kb3[0];
      short8 b3 = *(const short8*)&kb3[32];
      S0 = __builtin_amdgcn_mfma_f32_16x16x32_bf16(a0, Qf0, S0, 0, 0, 0);
      S1 = __builtin_amdgcn_mfma_f32_16x16x32_bf16(a1, Qf0, S1, 0, 0, 0);
      S2 = __builtin_amdgcn_mfma_f32_16x16x32_bf16(a2, Qf0, S2, 0, 0, 0);
      S3 = __builtin_amdgcn_mfma_f32_16x16x32_bf16(a3, Qf0, S3, 0, 0, 0);
      S0 = __builtin_amdgcn_mfma_f32_16x16x32_bf16(b0, Qf1, S0, 0, 0, 0);
      S1 = __builtin_amdgcn_mfma_f32_16x16x32_bf16(b1, Qf1, S1, 0, 0, 0);
      S2 = __builtin_amdgcn_mfma_f32_16x16x32_bf16(b2, Qf1, S2, 0, 0, 0);
      S3 = __builtin_amdgcn_mfma_f32_16x16x32_bf16(b3, Qf1, S3, 0, 0, 0);
    }
    // lane holds S(q=r16, k_local = 16*mb + 4*g + reg)
    float sc[4][4];
#pragma unroll
    for (int r = 0; r < 4; r++) {
      sc[0][r] = S0[r] * 0.125f; sc[1][r] = S1[r] * 0.125f;
      sc[2][r] = S2[r] * 0.125f; sc[3][r] = S3[r] * 0.125f;
    }
    if (kt == nkt - 1) {            // causal mask (only possible in last k-tile)
#pragma unroll
      for (int mb = 0; mb < 4; mb++)
#pragma unroll
        for (int r = 0; r < 4; r++)
          if (k0 + 16 * mb + 4 * g + r > q0 + r16) sc[mb][r] = -INFINITY;
    }
    // per-q running softmax (partial, this wave's keys only)
    float tm = sc[0][0];
#pragma unroll
    for (int mb = 0; mb < 4; mb++)
#pragma unroll
      for (int r = 0; r < 4; r++) tm = fmaxf(tm, sc[mb][r]);
    tm = fmaxf(tm, __shfl_xor(tm, 16));
    tm = fmaxf(tm, __shfl_xor(tm, 32));
    float mn = fmaxf(m, tm);
    float ef = __expf(m - mn);
    float pv[4][4];
    float ps = 0.f;
#pragma unroll
    for (int mb = 0; mb < 4; mb++)
#pragma unroll
      for (int r = 0; r < 4; r++) { pv[mb][r] = __expf(sc[mb][r] - mn); ps += pv[mb][r]; }
    ps += __shfl_xor(ps, 16);
    ps += __shfl_xor(ps, 32);
    ssum = ssum * ef + ps;
    m = mn;
#pragma unroll
    for (int r = 0; r < 4; r++) {
      float efr = __shfl(ef, 4 * g + r);
      O0[r] *= efr; O1[r] *= efr; O2[r] *= efr; O3[r] *= efr;
    }
    // ---- P A-fragments: ap[c][j] = P(q=r16, k=32c+8g+j) ----
    short8 ap[2];
#pragma unroll
    for (int c = 0; c < 2; c++) {
#pragma unroll
      for (int jb = 0; jb < 2; jb++) {
        int x = 2 * g + jb;              // k = 32c + 4x + rs
        int hi = x >> 2;                 // selects m-block 2c / 2c+1
        int src = r16 + 16 * (x & 3);
#pragma unroll
        for (int rs = 0; rs < 4; rs++) {
          float tl = __shfl(pv[2 * c][rs],     src);
          float th = __shfl(pv[2 * c + 1][rs], src);
          ap[c][jb * 4 + rs] = (short)f2b_rne(hi ? th : tl);
        }
      }
    }
    // ---- PV: O[16q][64d] += P[16q][64k] @ V[64k][64d], V^T direct from global ----
    {
      const u16* vb0 = vtb + (size_t)(hofs + r16) * 4096 + k0 + 8 * g;
#pragma unroll
      for (int c = 0; c < 2; c++) {
        short8 v0 = *(const short8*)&vb0[32 * c];
        short8 v1 = *(const short8*)&vb0[16 * 4096 + 32 * c];
        short8 v2 = *(const short8*)&vb0[32 * 4096 + 32 * c];
        short8 v3 = *(const short8*)&vb0[48 * 4096 + 32 * c];
        O0 = __builtin_amdgcn_mfma_f32_16x16x32_bf16(ap[c], v0, O0, 0, 0, 0);
        O1 = __builtin_amdgcn_mfma_f32_16x16x32_bf16(ap[c], v1, O1, 0, 0, 0);
        O2 = __builtin_amdgcn_mfma_f32_16x16x32_bf16(ap[c], v2, O2, 0, 0, 0);
        O3 = __builtin_amdgcn_mfma_f32_16x16x32_bf16(ap[c], v3, O3, 0, 0, 0);
      }
    }
  }

  // ---- write partials, merge 4 waves ----
#pragma unroll
  for (int r = 0; r < 4; r++) {
    int q = 4 * g + r;
    Obuf[w][q][r16 +  0] = O0[r];
    Obuf[w][q][r16 + 16] = O1[r];
    Obuf[w][q][r16 + 32] = O2[r];
    Obuf[w][q][r16 + 48] = O3[r];
  }
  if (l < 16) { msh[w][l] = m; ssh[w][l] = ssum; }
  __syncthreads();

  int t = threadIdx.x;
  int q = t >> 4, dc = (t & 15) * 4;
  float M = fmaxf(fmaxf(msh[0][q], msh[1][q]), fmaxf(msh[2][q], msh[3][q]));
  float e0 = __expf(msh[0][q] - M), e1 = __expf(msh[1][q] - M);
  float e2 = __expf(msh[2][q] - M), e3 = __expf(msh[3][q] - M);
  float Stot = e0 * ssh[0][q] + e1 * ssh[1][q] + e2 * ssh[2][q] + e3 * ssh[3][q];
  float inv = 1.f / Stot;
  float4 res;
#pragma unroll
  for (int dd = 0; dd < 4; dd++) {
    float o = e0 * Obuf[0][q][dc+dd] + e1 * Obuf[1][q][dc+dd]
            + e2 * Obuf[2][q][dc+dd] + e3 * Obuf[3][q][dc+dd];
    ((float*)&res)[dd] = o * inv;
  }
  *(float4*)&out[(size_t)(q0 + q) * EMB + hofs + dc] = res;
}

// ---------------- CSR build ----------------
__global__ void zero_i32(int* p, int n) {
  int i = blockIdx.x * 256 + threadIdx.x;
  if (i < n) p[i] = 0;
}
__global__ void hist_dst(const int* __restrict__ adj, int* __restrict__ cnt) {
  int e = blockIdx.x * 256 + threadIdx.x;
  if (e < NE) atomicAdd(&cnt[adj[NE + e]], 1);
}
__global__ __launch_bounds__(1024) void scan4096(const int* __restrict__ cnt, int* __restrict__ indptr,
                                                 int* __restrict__ cursor) {
  int t = threadIdx.x;
  int4 c = *reinterpret_cast<const int4*>(cnt + t * 4);
  int s0 = c.x, s1 = s0 + c.y, s2 = s1 + c.z, s3 = s2 + c.w;
  int lane = t & 63, w = t >> 6;
  int x = s3;
#pragma unroll
  for (int off = 1; off < 64; off <<= 1) {
    int y = __shfl_up(x, off);
    if (lane >= off) x += y;
  }
  __shared__ int wsum[16];
  if (lane == 63) wsum[w] = x;
  __syncthreads();
  if (t == 0) {
    int acc = 0;
    for (int i = 0; i < 16; i++) { int tv = wsum[i]; wsum[i] = acc; acc += tv; }
  }
  __syncthreads();
  int b = wsum[w] + x - s3;
  indptr[t*4+0] = b;      indptr[t*4+1] = b + s0;
  indptr[t*4+2] = b + s1; indptr[t*4+3] = b + s2;
  cursor[t*4+0] = b;      cursor[t*4+1] = b + s0;
  cursor[t*4+2] = b + s1; cursor[t*4+3] = b + s2;
  if (t == 1023) indptr[4096] = b + s3;
}
__global__ void scatter_edges(const int* __restrict__ adj, int* __restrict__ cursor, int* __restrict__ esrc) {
  int e = blockIdx.x * 256 + threadIdx.x;
  if (e < NE) {
    int dst = adj[NE + e];
    int pos = atomicAdd(&cursor[dst], 1);
    esrc[pos] = adj[e];
  }
}

// ---------------- TransformerConv aggregation ----------------
__global__ __launch_bounds__(256) void conv_agg(const float* __restrict__ qb, const float* __restrict__ kb,
                                                const float* __restrict__ vb, const int* __restrict__ indptr,
                                                const int* __restrict__ esrc, float* __restrict__ y) {
  __shared__ float q_s[EMB];
  int n = blockIdx.x;
  int tid = threadIdx.x;
  int h = tid >> 6, lane = tid & 63;
  q_s[tid] = qb[(size_t)n * EMB + tid];
  __syncthreads();
  int start = indptr[n], end = indptr[n + 1];
  float m = -INFINITY, s = 0.f, o = 0.f;
  for (int p0 = start; p0 < end; p0 += 64) {
    int nk = end - p0; if (nk > 64) nk = 64;
    int src = 0;
    float sc = -INFINITY;
    if (lane < nk) {
      src = esrc[p0 + lane];
      const float* kr = kb + (size_t)src * EMB + h * HD;
      const float* qh = &q_s[h * HD];
      float acc = 0.f;
#pragma unroll
      for (int d = 0; d < HD; d += 4) {
        float4 k4 = load4f(kr + d);
        float4 q4 = *reinterpret_cast<const float4*>(qh + d);
        acc = fmaf(k4.x, q4.x, acc); acc = fmaf(k4.y, q4.y, acc);
        acc = fmaf(k4.z, q4.z, acc); acc = fmaf(k4.w, q4.w, acc);
      }
      sc = acc * 0.125f;
    }
    float bm = sc;
#pragma unroll
    for (int off = 32; off; off >>= 1) bm = fmaxf(bm, __shfl_xor(bm, off));
    float mn = fmaxf(m, bm);
    float scale = __expf(m - mn);
    float p = (lane < nk) ? __expf(sc - mn) : 0.f;
    float ps = p;
#pragma unroll
    for (int off = 32; off; off >>= 1) ps += __shfl_xor(ps, off);
    s = s * scale + ps;
    o = o * scale;
    const float* vl = vb + h * HD + lane;
    for (int jj = 0; jj < nk; jj++) {
      int   sj = __shfl(src, jj);
      float pj = __shfl(p, jj);
      o = fmaf(pj, vl[(size_t)sj * EMB], o);
    }
    m = mn;
  }
  float agg = o / (s + 1e-16f);
  y[(size_t)n * EMB + h * HD + lane] += agg;
}

// ---------------- instance norm + lrelu + sanitize ----------------
__global__ __launch_bounds__(256) void colstats_partial(const float* __restrict__ y, float* __restrict__ part) {
  int c = threadIdx.x;
  int r0 = blockIdx.x * 128;
  float s = 0.f, q = 0.f;
  for (int r = r0; r < r0 + 128; r++) {
    float v = y[(size_t)r * EMB + c];
    s += v; q = fmaf(v, v, q);
  }
  part[blockIdx.x * 512 + c] = s;
  part[blockIdx.x * 512 + 256 + c] = q;
}
__global__ __launch_bounds__(256) void colstats_final(const float* __restrict__ part, float* __restrict__ stats) {
  int c = threadIdx.x;
  float s = 0.f, q = 0.f;
  for (int b = 0; b < 32; b++) { s += part[b * 512 + c]; q += part[b * 512 + 256 + c]; }
  float mean = s * (1.f / 4096.f);
  float var  = q * (1.f / 4096.f) - mean * mean;
  stats[c] = mean;
  stats[256 + c] = rsqrtf(var + 1e-5f);
}
__global__ __launch_bounds__(256) void norm_apply(const float* __restrict__ y, const float* __restrict__ stats,
                                                  float* __restrict__ f, int colOff) {
  int c = threadIdx.x;
  float mean = stats[c], rstd = stats[256 + c];
  int r0 = blockIdx.x * 16;
  for (int r = r0; r < r0 + 16; r++) {
    float v = (y[(size_t)r * EMB + c] - mean) * rstd;
    v = (v > 0.f) ? v : 0.2f * v;
    v = sanitize_f(v);
    f[(size_t)r * 512 + colOff + c] = v;
  }
}

// ---------------- classifier tail ----------------
__global__ __launch_bounds__(256) void final_softmax(const float* __restrict__ f1, const float* __restrict__ W2,
                                                     const float* __restrict__ b2, float* __restrict__ out) {
  int w = threadIdx.x >> 6, lane = threadIdx.x & 63;
  int row = blockIdx.x * 4 + w;
  const float* fr = f1 + (size_t)row * 128;
  float x0 = fr[lane], x1 = fr[lane + 64];
  float p0 = x0 * W2[lane]       + x1 * W2[64 + lane];
  float p1 = x0 * W2[128 + lane] + x1 * W2[192 + lane];
#pragma unroll
  for (int off = 32; off; off >>= 1) { p0 += __shfl_xor(p0, off); p1 += __shfl_xor(p1, off); }
  if (lane == 0) {
    float l0 = p0 + b2[0], l1 = p1 + b2[1];
    float mx = fmaxf(l0, l1);
    float e0 = __expf(l0 - mx), e1 = __expf(l1 - mx);
    float inv = 1.f / (e0 + e1);
    out[(size_t)row * 2 + 0] = l0;
    out[(size_t)row * 2 + 1] = l1;
    out[8192 + (size_t)row * 2 + 0] = e0 * inv;
    out[8192 + (size_t)row * 2 + 1] = e1 * inv;
  }
}

extern "C" void kernel_launch(void* const* d_in, const int* in_sizes, int n_in,
                              void* d_out, int out_size, void* d_ws, size_t ws_size,
                              hipStream_t stream) {
  const float* img   = (const float*)d_in[2];
  const int*   adj   = (const int*)d_in[3];
  const float* W_img = (const float*)d_in[4];  const float* b_img = (const float*)d_in[5];
  const float* W_qkv = (const float*)d_in[6];  const float* b_qkv = (const float*)d_in[7];
  const float* W_o   = (const float*)d_in[8];  const float* b_o   = (const float*)d_in[9];
  const float* Wq_o  = (const float*)d_in[10]; const float* bq_o  = (const float*)d_in[11];
  const float* Wk_o  = (const float*)d_in[12]; const float* bk_o  = (const float*)d_in[13];
  const float* Wv_o  = (const float*)d_in[14]; const float* bv_o  = (const float*)d_in[15];
  const float* Ws_o  = (const float*)d_in[16]; const float* bs_o  = (const float*)d_in[17];
  const float* Wq_a  = (const float*)d_in[18]; const float* bq_a  = (const float*)d_in[19];
  const float* Wk_a  = (const float*)d_in[20]; const float* bk_a  = (const float*)d_in[21];
  const float* Wv_a  = (const float*)d_in[22]; const float* bv_a  = (const float*)d_in[23];
  const float* Ws_a  = (const float*)d_in[24]; const float* bs_a  = (const float*)d_in[25];
  const float* W_c1  = (const float*)d_in[26]; const float* b_c1  = (const float*)d_in[27];
  const float* W_c2  = (const float*)d_in[28]; const float* b_c2  = (const float*)d_in[29];

  char* ws = (char*)d_ws;
  float* h     = (float*)(ws + 0);                    // 4 MB
  float* hattn = (float*)(ws + (4ull << 20));         // 4 MB (aliased as qkb during mha)
  float* qkv   = (float*)(ws + (8ull << 20));         // 12 MB
  float* y     = (float*)(ws + (20ull << 20));        // 4 MB
  float* f     = (float*)(ws + (24ull << 20));        // 8 MB
  float* f1    = (float*)(ws + (32ull << 20));        // 2 MB (aliased as vtb during mha)
  int*   indptr= (int*)  (ws + (34ull << 20));
  int*   cursor= (int*)  (ws + (34ull << 20) + 20480);
  int*   esrc  = (int*)  (ws + (34ull << 20) + 40960);
  float* part  = (float*)(ws + (34ull << 20) + 40960 + (1ull << 20));
  float* stats = (float*)(ws + (34ull << 20) + 40960 + (1ull << 20) + 65536);

  u16* qkb = (u16*)hattn;   // 4096*512*2 = 4 MB, dead after mha
  u16* vtb = (u16*)f1;      // 256*4096*2 = 2 MB, dead after mha

  float* qb = qkv;
  float* kb = qkv + (1u << 20);
  float* vb = qkv + (2u << 20);

  dim3 b256(256);

  // 1. h = img_feat @ W_img^T + b_img
  gemm_bias<0><<<dim3(64, 4), b256, 0, stream>>>(img, W_img, b_img, h, NN, 256, 2048);
  // 2. qkv = h @ W_qkv^T + b_qkv
  gemm_bias<0><<<dim3(64, 12), b256, 0, stream>>>(h, W_qkv, b_qkv, qkv, NN, 768, 256);
  // 3. causal MHA (MFMA flash, split-K) -> y
  conv_qk<<<1024, b256, 0, stream>>>(qkv, qkb);
  conv_vt<<<256, b256, 0, stream>>>(qkv, vtb);
  mha_mfma2<<<1024, b256, 0, stream>>>(qkb, vtb, y);
  // 4. h_attn = sanitize(y @ W_o^T + b_o)
  gemm_bias<1><<<dim3(64, 4), b256, 0, stream>>>(y, W_o, b_o, hattn, NN, 256, 256);
  // 5. CSR of video_adj_list grouped by dst
  zero_i32<<<16, b256, 0, stream>>>(cursor, NN);
  hist_dst<<<NE / 256, b256, 0, stream>>>(adj, cursor);
  scan4096<<<1, 1024, 0, stream>>>(cursor, indptr, cursor);
  scatter_edges<<<NE / 256, b256, 0, stream>>>(adj, cursor, esrc);

  // 6. conv path O (input h)
  gemm_bias<0><<<dim3(64, 4), b256, 0, stream>>>(h, Wq_o, bq_o, qb, NN, 256, 256);
  gemm_bias<0><<<dim3(64, 4), b256, 0, stream>>>(h, Wk_o, bk_o, kb, NN, 256, 256);
  gemm_bias<0><<<dim3(64, 4), b256, 0, stream>>>(h, Wv_o, bv_o, vb, NN, 256, 256);
  gemm_bias<0><<<dim3(64, 4), b256, 0, stream>>>(h, Ws_o, bs_o, y,  NN, 256, 256);
  conv_agg<<<NN, b256, 0, stream>>>(qb, kb, vb, indptr, esrc, y);
  colstats_partial<<<32, b256, 0, stream>>>(y, part);
  colstats_final<<<1, b256, 0, stream>>>(part, stats);
  norm_apply<<<256, b256, 0, stream>>>(y, stats, f, 0);

  // 7. conv path A (input h_attn)
  gemm_bias<0><<<dim3(64, 4), b256, 0, stream>>>(hattn, Wq_a, bq_a, qb, NN, 256, 256);
  gemm_bias<0><<<dim3(64, 4), b256, 0, stream>>>(hattn, Wk_a, bk_a, kb, NN, 256, 256);
  gemm_bias<0><<<dim3(64, 4), b256, 0, stream>>>(hattn, Wv_a, bv_a, vb, NN, 256, 256);
  gemm_bias<0><<<dim3(64, 4), b256, 0, stream>>>(hattn, Ws_a, bs_a, y,  NN, 256, 256);
  conv_agg<<<NN, b256, 0, stream>>>(qb, kb, vb, indptr, esrc, y);
  colstats_partial<<<32, b256, 0, stream>>>(y, part);
  colstats_final<<<1, b256, 0, stream>>>(part, stats);
  norm_apply<<<256, b256, 0, stream>>>(y, stats, f, 256);

  // 8. f1 = lrelu(f @ W_c1^T + b_c1)
  gemm_bias<2><<<dim3(64, 2), b256, 0, stream>>>(f, W_c1, b_c1, f1, NN, 128, 512);
  // 9. logits + softmax -> out (f32): [0:8192] logits, [8192:16384] probs
  final_softmax<<<NN / 4, b256, 0, stream>>>(f1, W_c2, b_c2, (float*)d_out);
}

// Round 6
// 464.795 us; speedup vs baseline: 4.6382x; 1.3321x over previous
//
#include <hip/hip_runtime.h>
#include <hip/hip_bf16.h>

typedef unsigned short u16;
typedef unsigned int   u32;
typedef __attribute__((ext_vector_type(8))) short short8;
typedef __attribute__((ext_vector_type(4))) float f32x4;

#define NN 4096        // nodes
#define NE 262144      // edges
#define EMB 256
#define NH 4
#define HD 64

__device__ __forceinline__ float4 load4f(const float* p) { return *reinterpret_cast<const float4*>(p); }
__device__ __forceinline__ float sanitize_f(float v) {
  v = (v != v) ? 0.f : v;                 // nan -> 0
  return fminf(fmaxf(v, -1000.f), 1000.f); // +-inf and clip -> +-1000
}
__device__ __forceinline__ u16 f2b_rne(float x) {          // f32 -> bf16 bits, round-nearest-even
  u32 b = __float_as_uint(x);
  b += 0x7fff + ((b >> 16) & 1);
  return (u16)(b >> 16);
}
__device__ __forceinline__ u32 pack2(float a, float b) {
  return (u32)f2b_rne(a) | ((u32)f2b_rne(b) << 16);
}

// ================= generic MFMA GEMM: out = act(A[M,K] @ W^T + bias) =================
// Per 64-col n-tile descriptor (lets one dispatch cover several weight matrices).
struct GTile {
  const float* W;     // 64 weight rows for this tile: [64][K]
  const float* bias;  // 64 entries
  float*       out;
  int          colOff;
  int          ldOut;
};
struct GArgs { GTile t[16]; };

// 256 threads = 4 waves; block tile 64x64; wave tile 32x32 (2x2 frags of 16x16x32).
// LDS row stride 40 shorts (80 B): 16B-aligned, lanes 0..7 hit 8 distinct 16B slots mod 128.
template<int ACT>   // 0 none, 1 sanitize, 2 lrelu(0.2)
__global__ __launch_bounds__(256) void gemm_mfma(const float* __restrict__ A, const GArgs ga, int K) {
  __shared__ short As[64 * 40];
  __shared__ short Bs[64 * 40];
  const int t = threadIdx.x;
  const int bm = blockIdx.x * 64;
  const GTile tl = ga.t[blockIdx.y];
  const int w = t >> 6, l = t & 63, g = l >> 4, r16 = l & 15;
  const int wr = w >> 1, wc = w & 1;
  const int lrow = t >> 2, lseg = (t & 3) * 8;

  const float* Ap = A + (size_t)(bm + lrow) * K + lseg;
  const float* Wp = tl.W + (size_t)lrow * K + lseg;

  f32x4 acc[2][2] = {{{0.f,0.f,0.f,0.f},{0.f,0.f,0.f,0.f}},{{0.f,0.f,0.f,0.f},{0.f,0.f,0.f,0.f}}};
  for (int k0 = 0; k0 < K; k0 += 32) {
    float4 a0 = load4f(Ap + k0), a1 = load4f(Ap + k0 + 4);
    float4 b0 = load4f(Wp + k0), b1 = load4f(Wp + k0 + 4);
    __syncthreads();   // previous iteration's reads done
    *(uint4*)&As[lrow * 40 + lseg] =
        make_uint4(pack2(a0.x,a0.y), pack2(a0.z,a0.w), pack2(a1.x,a1.y), pack2(a1.z,a1.w));
    *(uint4*)&Bs[lrow * 40 + lseg] =
        make_uint4(pack2(b0.x,b0.y), pack2(b0.z,b0.w), pack2(b1.x,b1.y), pack2(b1.z,b1.w));
    __syncthreads();
    short8 af0 = *(const short8*)&As[(wr*32 +      r16) * 40 + 8*g];
    short8 af1 = *(const short8*)&As[(wr*32 + 16 + r16) * 40 + 8*g];
    short8 bf0 = *(const short8*)&Bs[(wc*32 +      r16) * 40 + 8*g];
    short8 bf1 = *(const short8*)&Bs[(wc*32 + 16 + r16) * 40 + 8*g];
    acc[0][0] = __builtin_amdgcn_mfma_f32_16x16x32_bf16(af0, bf0, acc[0][0], 0, 0, 0);
    acc[0][1] = __builtin_amdgcn_mfma_f32_16x16x32_bf16(af0, bf1, acc[0][1], 0, 0, 0);
    acc[1][0] = __builtin_amdgcn_mfma_f32_16x16x32_bf16(af1, bf0, acc[1][0], 0, 0, 0);
    acc[1][1] = __builtin_amdgcn_mfma_f32_16x16x32_bf16(af1, bf1, acc[1][1], 0, 0, 0);
  }
  const float bj[2] = { tl.bias[wc*32 + r16], tl.bias[wc*32 + 16 + r16] };
#pragma unroll
  for (int i = 0; i < 2; i++) {
#pragma unroll
    for (int j = 0; j < 2; j++) {
      int col = tl.colOff + wc*32 + 16*j + r16;
#pragma unroll
      for (int r = 0; r < 4; r++) {
        int row = bm + wr*32 + 16*i + 4*g + r;
        float v = acc[i][j][r] + bj[j];
        if (ACT == 1) v = sanitize_f(v);
        if (ACT == 2) v = (v > 0.f) ? v : 0.2f * v;
        tl.out[(size_t)row * tl.ldOut + col] = v;
      }
    }
  }
}

// ---------------- qkv f32 -> bf16 converts ----------------
__global__ __launch_bounds__(256) void conv_qk(const float* __restrict__ qkv, u16* __restrict__ qkb) {
  int i = (blockIdx.x * 256 + threadIdx.x) * 8;
  int n = i >> 9, c = i & 511;
  const float* p = qkv + (size_t)n * 768 + c;
  float4 a = load4f(p), b = load4f(p + 4);
  uint4 r = make_uint4(pack2(a.x, a.y), pack2(a.z, a.w), pack2(b.x, b.y), pack2(b.z, b.w));
  *(uint4*)&qkb[(size_t)n * 512 + c] = r;
}
__global__ __launch_bounds__(256) void conv_vt(const float* __restrict__ qkv, u16* __restrict__ vtb) {
  __shared__ u16 T[64][72];
  int t = threadIdx.x;
  int n0 = (blockIdx.x >> 2) * 64, c0 = (blockIdx.x & 3) * 64;
#pragma unroll
  for (int it = 0; it < 4; it++) {
    int nl = it * 16 + (t >> 4), c4 = (t & 15) * 4;
    float4 v = load4f(qkv + (size_t)(n0 + nl) * 768 + 512 + c0 + c4);
    T[nl][c4] = f2b_rne(v.x); T[nl][c4+1] = f2b_rne(v.y);
    T[nl][c4+2] = f2b_rne(v.z); T[nl][c4+3] = f2b_rne(v.w);
  }
  __syncthreads();
  int cl = t >> 2, chunk = t & 3;
  u16 buf[16];
#pragma unroll
  for (int j = 0; j < 16; j++) buf[j] = T[chunk * 16 + j][cl];
  *(uint4*)&vtb[(size_t)(c0 + cl) * 4096 + n0 + chunk * 16]     = *(uint4*)&buf[0];
  *(uint4*)&vtb[(size_t)(c0 + cl) * 4096 + n0 + chunk * 16 + 8] = *(uint4*)&buf[8];
}

// ---------------- causal MHA: MFMA flash, split-K over 4 waves ----------------
__global__ __launch_bounds__(256, 4) void mha_mfma2(const u16* __restrict__ qkb, const u16* __restrict__ vtb,
                                                    float* __restrict__ out) {
  __shared__ float Obuf[4][16][68];
  __shared__ float msh[4][16];
  __shared__ float ssh[4][16];
  const int bid  = blockIdx.x;
  const int h    = bid & 3;
  const int tile = 255 - (bid >> 2);
  const int q0   = tile * 16;
  const int w    = threadIdx.x >> 6;
  const int l    = threadIdx.x & 63;
  const int g    = l >> 4, r16 = l & 15;
  const int hofs = h * 64;

  const u16* qrow = qkb + (size_t)(q0 + r16) * 512 + hofs;
  short8 Qf0 = *(const short8*)&qrow[8 * g];
  short8 Qf1 = *(const short8*)&qrow[32 + 8 * g];

  f32x4 O0 = {0.f,0.f,0.f,0.f}, O1 = O0, O2 = O0, O3 = O0;
  float m = -INFINITY, ssum = 0.f;
  const int nkt = (q0 + 16 + 63) >> 6;

  for (int kt = w; kt < nkt; kt += 4) {
    const int k0 = kt * 64;
    f32x4 S0 = {0.f,0.f,0.f,0.f}, S1 = S0, S2 = S0, S3 = S0;
    {
      const u16* kb0 = qkb + (size_t)(k0 + r16) * 512 + 256 + hofs + 8 * g;
      short8 a0 = *(const short8*)&kb0[0];
      short8 b0 = *(const short8*)&kb0[32];
      const u16* kb1 = kb0 + (size_t)16 * 512;
      short8 a1 = *(const short8*)&kb1[0];
      short8 b1 = *(const short8*)&kb1[32];
      const u16* kb2 = kb1 + (size_t)16 * 512;
      short8 a2 = *(const short8*)&kb2[0];
      short8 b2 = *(const short8*)&kb2[32];
      const u16* kb3 = kb2 + (size_t)16 * 512;
      short8 a3 = *(const short8*)&kb3[0];
      short8 b3 = *(const short8*)&kb3[32];
      S0 = __builtin_amdgcn_mfma_f32_16x16x32_bf16(a0, Qf0, S0, 0, 0, 0);
      S1 = __builtin_amdgcn_mfma_f32_16x16x32_bf16(a1, Qf0, S1, 0, 0, 0);
      S2 = __builtin_amdgcn_mfma_f32_16x16x32_bf16(a2, Qf0, S2, 0, 0, 0);
      S3 = __builtin_amdgcn_mfma_f32_16x16x32_bf16(a3, Qf0, S3, 0, 0, 0);
      S0 = __builtin_amdgcn_mfma_f32_16x16x32_bf16(b0, Qf1, S0, 0, 0, 0);
      S1 = __builtin_amdgcn_mfma_f32_16x16x32_bf16(b1, Qf1, S1, 0, 0, 0);
      S2 = __builtin_amdgcn_mfma_f32_16x16x32_bf16(b2, Qf1, S2, 0, 0, 0);
      S3 = __builtin_amdgcn_mfma_f32_16x16x32_bf16(b3, Qf1, S3, 0, 0, 0);
    }
    float sc[4][4];
#pragma unroll
    for (int r = 0; r < 4; r++) {
      sc[0][r] = S0[r] * 0.125f; sc[1][r] = S1[r] * 0.125f;
      sc[2][r] = S2[r] * 0.125f; sc[3][r] = S3[r] * 0.125f;
    }
    if (kt == nkt - 1) {
#pragma unroll
      for (int mb = 0; mb < 4; mb++)
#pragma unroll
        for (int r = 0; r < 4; r++)
          if (k0 + 16 * mb + 4 * g + r > q0 + r16) sc[mb][r] = -INFINITY;
    }
    float tm = sc[0][0];
#pragma unroll
    for (int mb = 0; mb < 4; mb++)
#pragma unroll
      for (int r = 0; r < 4; r++) tm = fmaxf(tm, sc[mb][r]);
    tm = fmaxf(tm, __shfl_xor(tm, 16));
    tm = fmaxf(tm, __shfl_xor(tm, 32));
    float mn = fmaxf(m, tm);
    float ef = __expf(m - mn);
    float pv[4][4];
    float ps = 0.f;
#pragma unroll
    for (int mb = 0; mb < 4; mb++)
#pragma unroll
      for (int r = 0; r < 4; r++) { pv[mb][r] = __expf(sc[mb][r] - mn); ps += pv[mb][r]; }
    ps += __shfl_xor(ps, 16);
    ps += __shfl_xor(ps, 32);
    ssum = ssum * ef + ps;
    m = mn;
#pragma unroll
    for (int r = 0; r < 4; r++) {
      float efr = __shfl(ef, 4 * g + r);
      O0[r] *= efr; O1[r] *= efr; O2[r] *= efr; O3[r] *= efr;
    }
    short8 ap[2];
#pragma unroll
    for (int c = 0; c < 2; c++) {
#pragma unroll
      for (int jb = 0; jb < 2; jb++) {
        int x = 2 * g + jb;
        int hi = x >> 2;
        int src = r16 + 16 * (x & 3);
#pragma unroll
        for (int rs = 0; rs < 4; rs++) {
          float tl_ = __shfl(pv[2 * c][rs],     src);
          float th_ = __shfl(pv[2 * c + 1][rs], src);
          ap[c][jb * 4 + rs] = (short)f2b_rne(hi ? th_ : tl_);
        }
      }
    }
    {
      const u16* vb0 = vtb + (size_t)(hofs + r16) * 4096 + k0 + 8 * g;
#pragma unroll
      for (int c = 0; c < 2; c++) {
        short8 v0 = *(const short8*)&vb0[32 * c];
        short8 v1 = *(const short8*)&vb0[16 * 4096 + 32 * c];
        short8 v2 = *(const short8*)&vb0[32 * 4096 + 32 * c];
        short8 v3 = *(const short8*)&vb0[48 * 4096 + 32 * c];
        O0 = __builtin_amdgcn_mfma_f32_16x16x32_bf16(ap[c], v0, O0, 0, 0, 0);
        O1 = __builtin_amdgcn_mfma_f32_16x16x32_bf16(ap[c], v1, O1, 0, 0, 0);
        O2 = __builtin_amdgcn_mfma_f32_16x16x32_bf16(ap[c], v2, O2, 0, 0, 0);
        O3 = __builtin_amdgcn_mfma_f32_16x16x32_bf16(ap[c], v3, O3, 0, 0, 0);
      }
    }
  }

#pragma unroll
  for (int r = 0; r < 4; r++) {
    int q = 4 * g + r;
    Obuf[w][q][r16 +  0] = O0[r];
    Obuf[w][q][r16 + 16] = O1[r];
    Obuf[w][q][r16 + 32] = O2[r];
    Obuf[w][q][r16 + 48] = O3[r];
  }
  if (l < 16) { msh[w][l] = m; ssh[w][l] = ssum; }
  __syncthreads();

  int t = threadIdx.x;
  int q = t >> 4, dc = (t & 15) * 4;
  float M = fmaxf(fmaxf(msh[0][q], msh[1][q]), fmaxf(msh[2][q], msh[3][q]));
  float e0 = __expf(msh[0][q] - M), e1 = __expf(msh[1][q] - M);
  float e2 = __expf(msh[2][q] - M), e3 = __expf(msh[3][q] - M);
  float Stot = e0 * ssh[0][q] + e1 * ssh[1][q] + e2 * ssh[2][q] + e3 * ssh[3][q];
  float inv = 1.f / Stot;
  float4 res;
#pragma unroll
  for (int dd = 0; dd < 4; dd++) {
    float o = e0 * Obuf[0][q][dc+dd] + e1 * Obuf[1][q][dc+dd]
            + e2 * Obuf[2][q][dc+dd] + e3 * Obuf[3][q][dc+dd];
    ((float*)&res)[dd] = o * inv;
  }
  *(float4*)&out[(size_t)(q0 + q) * EMB + hofs + dc] = res;
}

// ---------------- CSR build ----------------
__global__ void zero_i32(int* p, int n) {
  int i = blockIdx.x * 256 + threadIdx.x;
  if (i < n) p[i] = 0;
}
__global__ void hist_dst(const int* __restrict__ adj, int* __restrict__ cnt) {
  int e = blockIdx.x * 256 + threadIdx.x;
  if (e < NE) atomicAdd(&cnt[adj[NE + e]], 1);
}
__global__ __launch_bounds__(1024) void scan4096(const int* __restrict__ cnt, int* __restrict__ indptr,
                                                 int* __restrict__ cursor) {
  int t = threadIdx.x;
  int4 c = *reinterpret_cast<const int4*>(cnt + t * 4);
  int s0 = c.x, s1 = s0 + c.y, s2 = s1 + c.z, s3 = s2 + c.w;
  int lane = t & 63, w = t >> 6;
  int x = s3;
#pragma unroll
  for (int off = 1; off < 64; off <<= 1) {
    int y = __shfl_up(x, off);
    if (lane >= off) x += y;
  }
  __shared__ int wsum[16];
  if (lane == 63) wsum[w] = x;
  __syncthreads();
  if (t == 0) {
    int acc = 0;
    for (int i = 0; i < 16; i++) { int tv = wsum[i]; wsum[i] = acc; acc += tv; }
  }
  __syncthreads();
  int b = wsum[w] + x - s3;
  indptr[t*4+0] = b;      indptr[t*4+1] = b + s0;
  indptr[t*4+2] = b + s1; indptr[t*4+3] = b + s2;
  cursor[t*4+0] = b;      cursor[t*4+1] = b + s0;
  cursor[t*4+2] = b + s1; cursor[t*4+3] = b + s2;
  if (t == 1023) indptr[4096] = b + s3;
}
__global__ void scatter_edges(const int* __restrict__ adj, int* __restrict__ cursor, int* __restrict__ esrc) {
  int e = blockIdx.x * 256 + threadIdx.x;
  if (e < NE) {
    int dst = adj[NE + e];
    int pos = atomicAdd(&cursor[dst], 1);
    esrc[pos] = adj[e];
  }
}

// ---------------- TransformerConv aggregation ----------------
__global__ __launch_bounds__(256) void conv_agg(const float* __restrict__ qb, const float* __restrict__ kb,
                                                const float* __restrict__ vb, const int* __restrict__ indptr,
                                                const int* __restrict__ esrc, float* __restrict__ y) {
  __shared__ float q_s[EMB];
  int n = blockIdx.x;
  int tid = threadIdx.x;
  int h = tid >> 6, lane = tid & 63;
  q_s[tid] = qb[(size_t)n * EMB + tid];
  __syncthreads();
  int start = indptr[n], end = indptr[n + 1];
  float m = -INFINITY, s = 0.f, o = 0.f;
  for (int p0 = start; p0 < end; p0 += 64) {
    int nk = end - p0; if (nk > 64) nk = 64;
    int src = 0;
    float sc = -INFINITY;
    if (lane < nk) {
      src = esrc[p0 + lane];
      const float* kr = kb + (size_t)src * EMB + h * HD;
      const float* qh = &q_s[h * HD];
      float acc = 0.f;
#pragma unroll
      for (int d = 0; d < HD; d += 4) {
        float4 k4 = load4f(kr + d);
        float4 q4 = *reinterpret_cast<const float4*>(qh + d);
        acc = fmaf(k4.x, q4.x, acc); acc = fmaf(k4.y, q4.y, acc);
        acc = fmaf(k4.z, q4.z, acc); acc = fmaf(k4.w, q4.w, acc);
      }
      sc = acc * 0.125f;
    }
    float bm = sc;
#pragma unroll
    for (int off = 32; off; off >>= 1) bm = fmaxf(bm, __shfl_xor(bm, off));
    float mn = fmaxf(m, bm);
    float scale = __expf(m - mn);
    float p = (lane < nk) ? __expf(sc - mn) : 0.f;
    float ps = p;
#pragma unroll
    for (int off = 32; off; off >>= 1) ps += __shfl_xor(ps, off);
    s = s * scale + ps;
    o = o * scale;
    const float* vl = vb + h * HD + lane;
    for (int jj = 0; jj < nk; jj++) {
      int   sj = __shfl(src, jj);
      float pj = __shfl(p, jj);
      o = fmaf(pj, vl[(size_t)sj * EMB], o);
    }
    m = mn;
  }
  float agg = o / (s + 1e-16f);
  y[(size_t)n * EMB + h * HD + lane] += agg;
}

// ---------------- instance norm + lrelu + sanitize ----------------
__global__ __launch_bounds__(256) void colstats_partial(const float* __restrict__ y, float* __restrict__ part) {
  int c = threadIdx.x;
  int r0 = blockIdx.x * 128;
  float s = 0.f, q = 0.f;
  for (int r = r0; r < r0 + 128; r++) {
    float v = y[(size_t)r * EMB + c];
    s += v; q = fmaf(v, v, q);
  }
  part[blockIdx.x * 512 + c] = s;
  part[blockIdx.x * 512 + 256 + c] = q;
}
__global__ __launch_bounds__(256) void colstats_final(const float* __restrict__ part, float* __restrict__ stats) {
  int c = threadIdx.x;
  float s = 0.f, q = 0.f;
  for (int b = 0; b < 32; b++) { s += part[b * 512 + c]; q += part[b * 512 + 256 + c]; }
  float mean = s * (1.f / 4096.f);
  float var  = q * (1.f / 4096.f) - mean * mean;
  stats[c] = mean;
  stats[256 + c] = rsqrtf(var + 1e-5f);
}
__global__ __launch_bounds__(256) void norm_apply(const float* __restrict__ y, const float* __restrict__ stats,
                                                  float* __restrict__ f, int colOff) {
  int c = threadIdx.x;
  float mean = stats[c], rstd = stats[256 + c];
  int r0 = blockIdx.x * 16;
  for (int r = r0; r < r0 + 16; r++) {
    float v = (y[(size_t)r * EMB + c] - mean) * rstd;
    v = (v > 0.f) ? v : 0.2f * v;
    v = sanitize_f(v);
    f[(size_t)r * 512 + colOff + c] = v;
  }
}

// ---------------- classifier tail ----------------
__global__ __launch_bounds__(256) void final_softmax(const float* __restrict__ f1, const float* __restrict__ W2,
                                                     const float* __restrict__ b2, float* __restrict__ out) {
  int w = threadIdx.x >> 6, lane = threadIdx.x & 63;
  int row = blockIdx.x * 4 + w;
  const float* fr = f1 + (size_t)row * 128;
  float x0 = fr[lane], x1 = fr[lane + 64];
  float p0 = x0 * W2[lane]       + x1 * W2[64 + lane];
  float p1 = x0 * W2[128 + lane] + x1 * W2[192 + lane];
#pragma unroll
  for (int off = 32; off; off >>= 1) { p0 += __shfl_xor(p0, off); p1 += __shfl_xor(p1, off); }
  if (lane == 0) {
    float l0 = p0 + b2[0], l1 = p1 + b2[1];
    float mx = fmaxf(l0, l1);
    float e0 = __expf(l0 - mx), e1 = __expf(l1 - mx);
    float inv = 1.f / (e0 + e1);
    out[(size_t)row * 2 + 0] = l0;
    out[(size_t)row * 2 + 1] = l1;
    out[8192 + (size_t)row * 2 + 0] = e0 * inv;
    out[8192 + (size_t)row * 2 + 1] = e1 * inv;
  }
}

extern "C" void kernel_launch(void* const* d_in, const int* in_sizes, int n_in,
                              void* d_out, int out_size, void* d_ws, size_t ws_size,
                              hipStream_t stream) {
  const float* img   = (const float*)d_in[2];
  const int*   adj   = (const int*)d_in[3];
  const float* W_img = (const float*)d_in[4];  const float* b_img = (const float*)d_in[5];
  const float* W_qkv = (const float*)d_in[6];  const float* b_qkv = (const float*)d_in[7];
  const float* W_o   = (const float*)d_in[8];  const float* b_o   = (const float*)d_in[9];
  const float* Wq_o  = (const float*)d_in[10]; const float* bq_o  = (const float*)d_in[11];
  const float* Wk_o  = (const float*)d_in[12]; const float* bk_o  = (const float*)d_in[13];
  const float* Wv_o  = (const float*)d_in[14]; const float* bv_o  = (const float*)d_in[15];
  const float* Ws_o  = (const float*)d_in[16]; const float* bs_o  = (const float*)d_in[17];
  const float* Wq_a  = (const float*)d_in[18]; const float* bq_a  = (const float*)d_in[19];
  const float* Wk_a  = (const float*)d_in[20]; const float* bk_a  = (const float*)d_in[21];
  const float* Wv_a  = (const float*)d_in[22]; const float* bv_a  = (const float*)d_in[23];
  const float* Ws_a  = (const float*)d_in[24]; const float* bs_a  = (const float*)d_in[25];
  const float* W_c1  = (const float*)d_in[26]; const float* b_c1  = (const float*)d_in[27];
  const float* W_c2  = (const float*)d_in[28]; const float* b_c2  = (const float*)d_in[29];

  char* ws = (char*)d_ws;
  float* h     = (float*)(ws + 0);                    // 4 MB
  float* hattn = (float*)(ws + (4ull << 20));         // 4 MB (aliased as qkb during mha)
  float* qkv   = (float*)(ws + (8ull << 20));         // 12 MB
  float* y     = (float*)(ws + (20ull << 20));        // 4 MB
  float* f     = (float*)(ws + (24ull << 20));        // 8 MB
  float* f1    = (float*)(ws + (32ull << 20));        // 2 MB (aliased as vtb during mha)
  int*   indptr= (int*)  (ws + (34ull << 20));
  int*   cursor= (int*)  (ws + (34ull << 20) + 20480);
  int*   esrc  = (int*)  (ws + (34ull << 20) + 40960);
  float* part  = (float*)(ws + (34ull << 20) + 40960 + (1ull << 20));
  float* stats = (float*)(ws + (34ull << 20) + 40960 + (1ull << 20) + 65536);

  u16* qkb = (u16*)hattn;   // dead after mha
  u16* vtb = (u16*)f1;      // dead after mha

  float* qb = qkv;
  float* kb = qkv + (1u << 20);
  float* vb = qkv + (2u << 20);

  dim3 b256(256);

  // 1. h = img_feat @ W_img^T + b_img   (M=4096,N=256,K=2048)
  {
    GArgs ga;
    for (int i = 0; i < 4; i++)
      ga.t[i] = { W_img + (size_t)i * 64 * 2048, b_img + i * 64, h, i * 64, 256 };
    gemm_mfma<0><<<dim3(64, 4), b256, 0, stream>>>(img, ga, 2048);
  }
  // 2. qkv = h @ W_qkv^T + b_qkv   (N=768,K=256)
  {
    GArgs ga;
    for (int i = 0; i < 12; i++)
      ga.t[i] = { W_qkv + (size_t)i * 64 * 256, b_qkv + i * 64, qkv, i * 64, 768 };
    gemm_mfma<0><<<dim3(64, 12), b256, 0, stream>>>(h, ga, 256);
  }
  // 3. causal MHA (MFMA flash, split-K) -> y
  conv_qk<<<1024, b256, 0, stream>>>(qkv, qkb);
  conv_vt<<<256, b256, 0, stream>>>(qkv, vtb);
  mha_mfma2<<<1024, b256, 0, stream>>>(qkb, vtb, y);
  // 4. h_attn = sanitize(y @ W_o^T + b_o)
  {
    GArgs ga;
    for (int i = 0; i < 4; i++)
      ga.t[i] = { W_o + (size_t)i * 64 * 256, b_o + i * 64, hattn, i * 64, 256 };
    gemm_mfma<1><<<dim3(64, 4), b256, 0, stream>>>(y, ga, 256);
  }
  // 5. CSR of video_adj_list grouped by dst
  zero_i32<<<16, b256, 0, stream>>>(cursor, NN);
  hist_dst<<<NE / 256, b256, 0, stream>>>(adj, cursor);
  scan4096<<<1, 1024, 0, stream>>>(cursor, indptr, cursor);
  scatter_edges<<<NE / 256, b256, 0, stream>>>(adj, cursor, esrc);

  // 6. conv path O: q/k/v/skip fused (N=1024,K=256), input h
  {
    const float* Wg[4] = { Wq_o, Wk_o, Wv_o, Ws_o };
    const float* bg[4] = { bq_o, bk_o, bv_o, bs_o };
    float*       og[4] = { qb, kb, vb, y };
    GArgs ga;
    for (int i = 0; i < 16; i++) {
      int gdx = i >> 2, li = i & 3;
      ga.t[i] = { Wg[gdx] + (size_t)li * 64 * 256, bg[gdx] + li * 64, og[gdx], li * 64, 256 };
    }
    gemm_mfma<0><<<dim3(64, 16), b256, 0, stream>>>(h, ga, 256);
  }
  conv_agg<<<NN, b256, 0, stream>>>(qb, kb, vb, indptr, esrc, y);
  colstats_partial<<<32, b256, 0, stream>>>(y, part);
  colstats_final<<<1, b256, 0, stream>>>(part, stats);
  norm_apply<<<256, b256, 0, stream>>>(y, stats, f, 0);

  // 7. conv path A: same, input hattn
  {
    const float* Wg[4] = { Wq_a, Wk_a, Wv_a, Ws_a };
    const float* bg[4] = { bq_a, bk_a, bv_a, bs_a };
    float*       og[4] = { qb, kb, vb, y };
    GArgs ga;
    for (int i = 0; i < 16; i++) {
      int gdx = i >> 2, li = i & 3;
      ga.t[i] = { Wg[gdx] + (size_t)li * 64 * 256, bg[gdx] + li * 64, og[gdx], li * 64, 256 };
    }
    gemm_mfma<0><<<dim3(64, 16), b256, 0, stream>>>(hattn, ga, 256);
  }
  conv_agg<<<NN, b256, 0, stream>>>(qb, kb, vb, indptr, esrc, y);
  colstats_partial<<<32, b256, 0, stream>>>(y, part);
  colstats_final<<<1, b256, 0, stream>>>(part, stats);
  norm_apply<<<256, b256, 0, stream>>>(y, stats, f, 256);

  // 8. f1 = lrelu(f @ W_c1^T + b_c1)   (N=128,K=512)
  {
    GArgs ga;
    for (int i = 0; i < 2; i++)
      ga.t[i] = { W_c1 + (size_t)i * 64 * 512, b_c1 + i * 64, f1, i * 64, 128 };
    gemm_mfma<2><<<dim3(64, 2), b256, 0, stream>>>(f, ga, 512);
  }
  // 9. logits + softmax -> out (f32): [0:8192] logits, [8192:16384] probs
  final_softmax<<<NN / 4, b256, 0, stream>>>(f1, W_c2, b_c2, (float*)d_out);
}